// Round 1
// baseline (1080.258 us; speedup 1.0000x reference)
//
#include <hip/hip_runtime.h>
#include <hip/hip_bf16.h>

// ---------------- problem constants ----------------
constexpr int Bn = 8, Cn = 128, Hn = 64, Wn = 64, HWn = Hn * Wn;
constexpr int DGn = 8, Kn = 9, CMn = 216;          // CM = DG*3*K
constexpr int Hs = 32, Ws = 32, HWs = Hs * Ws;

// ---------------- workspace layout (float offsets) ----------------
constexpr long OFF_FLAG = 0;                        // int flag at word 0
constexpr long OFF_FL   = 256;                      // feat_l f32   [8][128][4096]
constexpr long OFF_FS   = OFF_FL  + (long)Bn*Cn*HWn;      // feat_s f32 [8][128][1024]
constexpr long OFF_W1T  = OFF_FS  + (long)Bn*Cn*HWs;      // w1t [b][c][o] 8*128*128
constexpr long OFF_WOT  = OFF_W1T + (long)Bn*Cn*Cn;       // w_offT [c 256][o 128] (2x folded)
constexpr long OFF_WCT  = OFF_WOT + (long)2*Cn*Cn;        // w_cmT [c 128][k 9][oc 224]
constexpr long OFF_WDT  = OFF_WCT + (long)Cn*Kn*224;      // w_dcnT [k][c][o] 9*128*128
constexpr long OFF_BCM  = OFF_WDT + (long)Kn*Cn*Cn;       // b_cm (216, padded 256)
constexpr long OFF_BDC  = OFF_BCM + 256;                  // b_dcn (128, padded 256)
constexpr long OFF_GAP  = OFF_BDC + 256;                  // gap [b][c]
constexpr long OFF_AT   = OFF_GAP + (long)Bn*Cn;          // 1+sigmoid(atten) [b][c]
constexpr long OFF_FUP  = OFF_AT  + (long)Bn*Cn;          // feat_up f32 [8][128][4096]
constexpr long OFF_ARM  = OFF_FUP + (long)Bn*Cn*HWn;      // feat_arm f32
constexpr long OFF_OFT  = OFF_ARM + (long)Bn*Cn*HWn;      // off_feat f32
constexpr long OFF_OM   = OFF_OFT + (long)Bn*Cn*HWn;      // om f32 [8][216][4096] (mask sigmoided)
// total = OFF_OM + 8*216*4096 = 25,475,840 floats ~ 97.2 MiB

static __device__ __forceinline__ float ldin(const void* p, long i, bool isbf) {
  if (isbf) return __bfloat162float(((const __hip_bfloat16*)p)[i]);
  return ((const float*)p)[i];
}

// ---------------- dtype detector ----------------
// If buffer holds bf16 pairs, low 16 bits of each u32 are a bf16 of ~N(0,1):
// exponent bits [14:7] fall in [118,130] with prob ~0.999. For f32 data those
// bits are random mantissa bits: prob ~13/256. 1024 samples => clean split.
__global__ __launch_bounds__(256) void k_detect(const unsigned int* __restrict__ p,
                                                int* __restrict__ flag) {
  __shared__ int cnt[256];
  int t = threadIdx.x;
  int c = 0;
  for (int i = 0; i < 4; ++i) {
    unsigned v = p[t * 4 + i];
    unsigned e = (v >> 7) & 0xFFu;
    c += (e >= 118u && e <= 130u) ? 1 : 0;
  }
  cnt[t] = c;
  __syncthreads();
  for (int s = 128; s > 0; s >>= 1) {
    if (t < s) cnt[t] += cnt[t + s];
    __syncthreads();
  }
  if (t == 0) *flag = (cnt[0] > 512) ? 1 : 0;
}

// ---------------- input conversion ----------------
__global__ __launch_bounds__(256) void k_cvt(const void* __restrict__ src,
                                             float* __restrict__ dst, int n,
                                             const int* __restrict__ flag) {
  int stride = gridDim.x * blockDim.x;
  int i0 = blockIdx.x * blockDim.x + threadIdx.x;
  if (*flag) {
    const __hip_bfloat16* s = (const __hip_bfloat16*)src;
    for (int i = i0; i < n; i += stride) dst[i] = __bfloat162float(s[i]);
  } else {
    const float* s = (const float*)src;
    for (int i = i0; i < n; i += stride) dst[i] = s[i];
  }
}

// w_off [o 128][c 256] -> [c 256][o 128], with 2.0x folded for c>=128
__global__ __launch_bounds__(256) void k_woffT(const void* __restrict__ src,
                                               float* __restrict__ dst,
                                               const int* __restrict__ flag) {
  int i = blockIdx.x * 256 + threadIdx.x;
  if (i >= 2 * Cn * Cn) return;
  int c = i >> 7, o = i & 127;
  bool isbf = (*flag != 0);
  float v = ldin(src, (long)o * 256 + c, isbf);
  if (c >= Cn) v *= 2.0f;
  dst[i] = v;
}

// w_cm [oc 216][c 128][k 9] -> [c][k][oc padded to 224]
__global__ __launch_bounds__(256) void k_wcmT(const void* __restrict__ src,
                                              float* __restrict__ dst,
                                              const int* __restrict__ flag) {
  int i = blockIdx.x * 256 + threadIdx.x;
  if (i >= CMn * Cn * Kn) return;
  int oc = i / (Cn * Kn);
  int c = (i / Kn) % Cn;
  int k = i % Kn;
  bool isbf = (*flag != 0);
  dst[((long)c * Kn + k) * 224 + oc] = ldin(src, i, isbf);
}

// w_dcn [o 128][c 128][k 9] -> [k][c][o]
__global__ __launch_bounds__(256) void k_wdcnT(const void* __restrict__ src,
                                               float* __restrict__ dst,
                                               const int* __restrict__ flag) {
  int i = blockIdx.x * 256 + threadIdx.x;
  if (i >= Kn * Cn * Cn) return;
  int k = i / (Cn * Cn);
  int c = (i >> 7) & 127;
  int o = i & 127;
  bool isbf = (*flag != 0);
  dst[i] = ldin(src, ((long)o * Cn + c) * Kn + k, isbf);
}

// ---------------- gap (global average pool) ----------------
__global__ __launch_bounds__(256) void k_gap(const float* __restrict__ fl,
                                             float* __restrict__ gap) {
  __shared__ float red[256];
  int bc = blockIdx.x, t = threadIdx.x;
  const float* p = fl + (long)bc * HWn;
  float s = 0.f;
  for (int i = t; i < HWn; i += 256) s += p[i];
  red[t] = s;
  __syncthreads();
  for (int k = 128; k > 0; k >>= 1) {
    if (t < k) red[t] += red[t + k];
    __syncthreads();
  }
  if (t == 0) gap[bc] = red[0] * (1.0f / HWn);
}

// ---------------- atten: 1 + sigmoid(gap @ w_atten.T) ----------------
__global__ __launch_bounds__(256) void k_atten(const float* __restrict__ gap,
                                               const void* __restrict__ wat,
                                               float* __restrict__ at1p,
                                               const int* __restrict__ flag) {
  int tid = blockIdx.x * 256 + threadIdx.x;
  if (tid >= Bn * Cn) return;
  int b = tid >> 7, o = tid & 127;
  bool isbf = (*flag != 0);
  const float* g = gap + b * Cn;
  float s = 0.f;
  for (int c = 0; c < Cn; ++c) s += g[c] * ldin(wat, (long)o * Cn + c, isbf);
  at1p[tid] = 1.0f + 1.0f / (1.0f + expf(-s));
}

// w1t[b][c][o] = w_fsm[o][c] * (1 + atten[b][c])
__global__ __launch_bounds__(256) void k_w1t(const void* __restrict__ wfsm,
                                             const float* __restrict__ at1p,
                                             float* __restrict__ dst,
                                             const int* __restrict__ flag) {
  int i = blockIdx.x * 256 + threadIdx.x;
  if (i >= Bn * Cn * Cn) return;
  int b = i >> 14, c = (i >> 7) & 127, o = i & 127;
  bool isbf = (*flag != 0);
  dst[i] = ldin(wfsm, (long)o * Cn + c, isbf) * at1p[b * Cn + c];
}

// ---------------- bilinear 2x upsample (half-pixel, edge clamp) ----------------
__global__ __launch_bounds__(256) void k_up(const float* __restrict__ fs,
                                            float* __restrict__ fup) {
  int idx = blockIdx.x * 256 + threadIdx.x;
  if (idx >= Bn * Cn * HWn) return;
  int w = idx & 63, h = (idx >> 6) & 63, bc = idx >> 12;
  const float* s = fs + (long)bc * HWs;
  int iy0; float fy;
  if (h & 1) { iy0 = (h - 1) >> 1; fy = 0.25f; } else { iy0 = (h >> 1) - 1; fy = 0.75f; }
  int ix0; float fx;
  if (w & 1) { ix0 = (w - 1) >> 1; fx = 0.25f; } else { ix0 = (w >> 1) - 1; fx = 0.75f; }
  int iy1 = min(iy0 + 1, Hs - 1); iy0 = max(iy0, 0);
  int ix1 = min(ix0 + 1, Ws - 1); ix0 = max(ix0, 0);
  float v = (1.f - fy) * ((1.f - fx) * s[iy0 * Ws + ix0] + fx * s[iy0 * Ws + ix1]) +
            fy        * ((1.f - fx) * s[iy1 * Ws + ix0] + fx * s[iy1 * Ws + ix1]);
  fup[idx] = v;
}

// ---------------- feat_arm: 1x1 conv with per-batch gated weights ----------------
__global__ __launch_bounds__(256) void k_farm(const float* __restrict__ fl,
                                              const float* __restrict__ w1t,
                                              float* __restrict__ farm) {
  const int t = threadIdx.x;
  const int b = blockIdx.z, og = blockIdx.y;
  const int pos = blockIdx.x * 256 + t;
  const float* x = fl + (long)b * Cn * HWn + pos;
  const float* wb = w1t + (long)b * Cn * Cn + og * 8;
  float acc[8];
#pragma unroll
  for (int o = 0; o < 8; ++o) acc[o] = 0.f;
  for (int c = 0; c < Cn; ++c) {
    float xv = x[(long)c * HWn];
    const float4* w4 = (const float4*)(wb + (long)c * Cn);
    float4 wa = w4[0], wc = w4[1];
    acc[0] += xv * wa.x; acc[1] += xv * wa.y; acc[2] += xv * wa.z; acc[3] += xv * wa.w;
    acc[4] += xv * wc.x; acc[5] += xv * wc.y; acc[6] += xv * wc.z; acc[7] += xv * wc.w;
  }
#pragma unroll
  for (int o = 0; o < 8; ++o)
    farm[(long)(b * Cn + og * 8 + o) * HWn + pos] = acc[o];
}

// ---------------- off_feat: 1x1 conv over cat(feat_arm, 2*feat_up) ----------------
__global__ __launch_bounds__(256) void k_offf(const float* __restrict__ arm,
                                              const float* __restrict__ fup,
                                              const float* __restrict__ wot,
                                              float* __restrict__ oft) {
  const int t = threadIdx.x;
  const int b = blockIdx.z, og = blockIdx.y;
  const int pos = blockIdx.x * 256 + t;
  const float* xa = arm + (long)b * Cn * HWn + pos;
  const float* xu = fup + (long)b * Cn * HWn + pos;
  const float* wg = wot + og * 8;
  float acc[8];
#pragma unroll
  for (int o = 0; o < 8; ++o) acc[o] = 0.f;
  for (int c = 0; c < Cn; ++c) {
    float xv = xa[(long)c * HWn];
    const float4* w4 = (const float4*)(wg + (long)c * Cn);
    float4 wa = w4[0], wc = w4[1];
    acc[0] += xv * wa.x; acc[1] += xv * wa.y; acc[2] += xv * wa.z; acc[3] += xv * wa.w;
    acc[4] += xv * wc.x; acc[5] += xv * wc.y; acc[6] += xv * wc.z; acc[7] += xv * wc.w;
  }
  for (int c = 0; c < Cn; ++c) {
    float xv = xu[(long)c * HWn];
    const float4* w4 = (const float4*)(wg + (long)(Cn + c) * Cn);
    float4 wa = w4[0], wc = w4[1];
    acc[0] += xv * wa.x; acc[1] += xv * wa.y; acc[2] += xv * wa.z; acc[3] += xv * wa.w;
    acc[4] += xv * wc.x; acc[5] += xv * wc.y; acc[6] += xv * wc.z; acc[7] += xv * wc.w;
  }
#pragma unroll
  for (int o = 0; o < 8; ++o)
    oft[(long)(b * Cn + og * 8 + o) * HWn + pos] = acc[o];
}

// ---------------- 3x3 conv -> om (mask channels sigmoided) ----------------
__global__ __launch_bounds__(256) void k_convcm(const float* __restrict__ xin,
                                                const float* __restrict__ wcmT,
                                                const float* __restrict__ bcm,
                                                float* __restrict__ om) {
  __shared__ float xs[8][34][34];
  const int b = blockIdx.z, ocg = blockIdx.y, tile = blockIdx.x, t = threadIdx.x;
  const int ty0 = (tile >> 1) * 32, tx0 = (tile & 1) * 32;
  const int qx = t & 15, qy = t >> 4;
  float acc[8][2][2];
#pragma unroll
  for (int oc = 0; oc < 8; ++oc)
    for (int a = 0; a < 2; ++a)
      for (int d = 0; d < 2; ++d) acc[oc][a][d] = 0.f;

  for (int cc = 0; cc < 16; ++cc) {
    for (int i = t; i < 8 * 34 * 34; i += 256) {
      int c = i / 1156, rem = i % 1156, r = rem / 34, col = rem % 34;
      int gy = ty0 + r - 1, gx = tx0 + col - 1;
      float v = 0.f;
      if (gy >= 0 && gy < Hn && gx >= 0 && gx < Wn)
        v = xin[(long)(b * Cn + cc * 8 + c) * HWn + gy * Wn + gx];
      xs[c][r][col] = v;
    }
    __syncthreads();
    for (int c = 0; c < 8; ++c) {
      float xv[4][4];
#pragma unroll
      for (int r = 0; r < 4; ++r)
#pragma unroll
        for (int cl = 0; cl < 4; ++cl) xv[r][cl] = xs[c][2 * qy + r][2 * qx + cl];
      const float* wrow = wcmT + ((long)(cc * 8 + c) * Kn) * 224 + ocg * 8;
#pragma unroll
      for (int ky = 0; ky < 3; ++ky)
#pragma unroll
        for (int kx = 0; kx < 3; ++kx) {
          const float4* w4 = (const float4*)(wrow + (long)(ky * 3 + kx) * 224);
          float4 wa = w4[0], wc = w4[1];
          float wv[8] = {wa.x, wa.y, wa.z, wa.w, wc.x, wc.y, wc.z, wc.w};
#pragma unroll
          for (int oc = 0; oc < 8; ++oc) {
            acc[oc][0][0] += xv[ky][kx] * wv[oc];
            acc[oc][0][1] += xv[ky][kx + 1] * wv[oc];
            acc[oc][1][0] += xv[ky + 1][kx] * wv[oc];
            acc[oc][1][1] += xv[ky + 1][kx + 1] * wv[oc];
          }
        }
    }
    __syncthreads();
  }
#pragma unroll
  for (int oc = 0; oc < 8; ++oc) {
    int ch = ocg * 8 + oc;
    float bias = bcm[ch];
#pragma unroll
    for (int py = 0; py < 2; ++py)
#pragma unroll
      for (int px = 0; px < 2; ++px) {
        int gy = ty0 + 2 * qy + py, gx = tx0 + 2 * qx + px;
        float v = acc[oc][py][px] + bias;
        if (ch >= 144) v = 1.0f / (1.0f + expf(-v));   // mask channels
        om[(long)(b * CMn + ch) * HWn + gy * Wn + gx] = v;
      }
  }
}

// ---------------- fused deformable conv v2 + ReLU + residual ----------------
__global__ __launch_bounds__(256) void k_dcn(const float* __restrict__ om,
                                             const float* __restrict__ fup,
                                             const float* __restrict__ wdT,
                                             const float* __restrict__ bdc,
                                             const float* __restrict__ farm,
                                             void* __restrict__ out,
                                             const int* __restrict__ flagp) {
  __shared__ float wt4[4][DGn][64];
  __shared__ int   id4[4][DGn][64];
  __shared__ float val[Cn][64];
  const int h = blockIdx.x, b = blockIdx.y, t = threadIdx.x;
  const int w = t & 63, oq = t >> 6;               // 64 w-lanes x 4 o-quarters
  float acc[32];
#pragma unroll
  for (int p = 0; p < 32; ++p) acc[p] = 0.f;
  const float* omb = om + (long)b * CMn * HWn + h * Wn;

  for (int k = 0; k < Kn; ++k) {
    // Phase A: per (g, w) sampling weights & clamped indices
    for (int id = t; id < DGn * 64; id += 256) {
      int g = id >> 6, ww = id & 63;
      int ch = g * Kn + k;
      float oy = omb[(long)ch * HWn + ww];
      float ox = omb[(long)(72 + ch) * HWn + ww];
      float mk = omb[(long)(144 + ch) * HWn + ww];
      float py = (float)(h + k / 3 - 1) + oy;
      float px = (float)(ww + k % 3 - 1) + ox;
      float fy = floorf(py), fx = floorf(px);
      float ly = py - fy, lx = px - fx;
      int y0 = (int)fy, x0 = (int)fx;
      int y1 = y0 + 1, x1 = x0 + 1;
      float vy0 = (y0 >= 0 && y0 < Hn) ? 1.f : 0.f;
      float vy1 = (y1 >= 0 && y1 < Hn) ? 1.f : 0.f;
      float vx0 = (x0 >= 0 && x0 < Wn) ? 1.f : 0.f;
      float vx1 = (x1 >= 0 && x1 < Wn) ? 1.f : 0.f;
      int cy0 = min(max(y0, 0), Hn - 1), cy1 = min(max(y1, 0), Hn - 1);
      int cx0 = min(max(x0, 0), Wn - 1), cx1 = min(max(x1, 0), Wn - 1);
      wt4[0][g][ww] = (1.f - ly) * (1.f - lx) * vy0 * vx0 * mk;
      wt4[1][g][ww] = (1.f - ly) * lx * vy0 * vx1 * mk;
      wt4[2][g][ww] = ly * (1.f - lx) * vy1 * vx0 * mk;
      wt4[3][g][ww] = ly * lx * vy1 * vx1 * mk;
      id4[0][g][ww] = cy0 * Wn + cx0;
      id4[1][g][ww] = cy0 * Wn + cx1;
      id4[2][g][ww] = cy1 * Wn + cx0;
      id4[3][g][ww] = cy1 * Wn + cx1;
    }
    __syncthreads();
    // Phase B1: gather val[c][w]
    for (int j = 0; j < 32; ++j) {
      int id = j * 256 + t;
      int c = id >> 6, ww = id & 63, g = c >> 4;
      const float* base = fup + (long)(b * Cn + c) * HWn;
      float v = wt4[0][g][ww] * base[id4[0][g][ww]] +
                wt4[1][g][ww] * base[id4[1][g][ww]] +
                wt4[2][g][ww] * base[id4[2][g][ww]] +
                wt4[3][g][ww] * base[id4[3][g][ww]];
      val[c][ww] = v;
    }
    __syncthreads();
    // Phase B2: accumulate 32 outputs per thread
    const float* wk = wdT + (long)k * Cn * Cn + oq * 32;
    for (int c = 0; c < Cn; ++c) {
      float vv = val[c][w];
      const float4* w4 = (const float4*)(wk + (long)c * Cn);
#pragma unroll
      for (int q = 0; q < 8; ++q) {
        float4 wv = w4[q];
        acc[q * 4 + 0] += vv * wv.x;
        acc[q * 4 + 1] += vv * wv.y;
        acc[q * 4 + 2] += vv * wv.z;
        acc[q * 4 + 3] += vv * wv.w;
      }
    }
    __syncthreads();
  }

  // Epilogue: bias, relu, + feat_arm, store in detected dtype
  float bias[32];
  const float4* b4 = (const float4*)(bdc + oq * 32);
#pragma unroll
  for (int q = 0; q < 8; ++q) {
    float4 v = b4[q];
    bias[q * 4 + 0] = v.x; bias[q * 4 + 1] = v.y;
    bias[q * 4 + 2] = v.z; bias[q * 4 + 3] = v.w;
  }
  bool isbf = (*flagp != 0);
  if (isbf) {
    __hip_bfloat16* op = (__hip_bfloat16*)out;
#pragma unroll
    for (int p = 0; p < 32; ++p) {
      long oi = (long)(b * Cn + oq * 32 + p) * HWn + h * Wn + w;
      float v = acc[p] + bias[p];
      v = fmaxf(v, 0.f) + farm[oi];
      op[oi] = __float2bfloat16(v);
    }
  } else {
    float* op = (float*)out;
#pragma unroll
    for (int p = 0; p < 32; ++p) {
      long oi = (long)(b * Cn + oq * 32 + p) * HWn + h * Wn + w;
      float v = acc[p] + bias[p];
      v = fmaxf(v, 0.f) + farm[oi];
      op[oi] = v;
    }
  }
}

// ---------------- launcher ----------------
extern "C" void kernel_launch(void* const* d_in, const int* in_sizes, int n_in,
                              void* d_out, int out_size, void* d_ws, size_t ws_size,
                              hipStream_t stream) {
  (void)in_sizes; (void)n_in; (void)out_size; (void)ws_size;
  const void* feat_l  = d_in[0];
  const void* feat_s  = d_in[1];
  const void* w_atten = d_in[2];
  const void* w_fsm   = d_in[3];
  const void* w_off   = d_in[4];
  const void* w_cm    = d_in[5];
  const void* b_cm    = d_in[6];
  const void* w_dcn   = d_in[7];
  const void* b_dcn   = d_in[8];
  float* ws = (float*)d_ws;
  int* flagw = (int*)d_ws;
  const int* flag = (const int*)d_ws;

  k_detect<<<1, 256, 0, stream>>>((const unsigned int*)feat_l, flagw);
  k_cvt<<<2048, 256, 0, stream>>>(feat_l, ws + OFF_FL, Bn * Cn * HWn, flag);
  k_cvt<<<512, 256, 0, stream>>>(feat_s, ws + OFF_FS, Bn * Cn * HWs, flag);
  k_cvt<<<1, 256, 0, stream>>>(b_cm, ws + OFF_BCM, CMn, flag);
  k_cvt<<<1, 256, 0, stream>>>(b_dcn, ws + OFF_BDC, Cn, flag);
  k_woffT<<<(2 * Cn * Cn + 255) / 256, 256, 0, stream>>>(w_off, ws + OFF_WOT, flag);
  k_wcmT<<<(CMn * Cn * Kn + 255) / 256, 256, 0, stream>>>(w_cm, ws + OFF_WCT, flag);
  k_wdcnT<<<(Kn * Cn * Cn + 255) / 256, 256, 0, stream>>>(w_dcn, ws + OFF_WDT, flag);
  k_gap<<<Bn * Cn, 256, 0, stream>>>(ws + OFF_FL, ws + OFF_GAP);
  k_atten<<<4, 256, 0, stream>>>(ws + OFF_GAP, w_atten, ws + OFF_AT, flag);
  k_w1t<<<(Bn * Cn * Cn + 255) / 256, 256, 0, stream>>>(w_fsm, ws + OFF_AT, ws + OFF_W1T, flag);
  k_up<<<(Bn * Cn * HWn + 255) / 256, 256, 0, stream>>>(ws + OFF_FS, ws + OFF_FUP);
  k_farm<<<dim3(16, 16, 8), 256, 0, stream>>>(ws + OFF_FL, ws + OFF_W1T, ws + OFF_ARM);
  k_offf<<<dim3(16, 16, 8), 256, 0, stream>>>(ws + OFF_ARM, ws + OFF_FUP, ws + OFF_WOT, ws + OFF_OFT);
  k_convcm<<<dim3(4, 27, 8), 256, 0, stream>>>(ws + OFF_OFT, ws + OFF_WCT, ws + OFF_BCM, ws + OFF_OM);
  k_dcn<<<dim3(64, 8), 256, 0, stream>>>(ws + OFF_OM, ws + OFF_FUP, ws + OFF_WDT,
                                         ws + OFF_BDC, ws + OFF_ARM, d_out, flag);
}

// Round 2
// 654.510 us; speedup vs baseline: 1.6505x; 1.6505x over previous
//
#include <hip/hip_runtime.h>
#include <hip/hip_bf16.h>

// ---------------- problem constants ----------------
constexpr int Bn = 8, Cn = 128, Hn = 64, Wn = 64, HWn = Hn * Wn;
constexpr int DGn = 8, Kn = 9, CMn = 216;          // CM = DG*3*K
constexpr int Hs = 32, Ws = 32, HWs = Hs * Ws;

typedef __attribute__((ext_vector_type(8))) short bf16x8;
typedef __attribute__((ext_vector_type(4))) float f32x4;

// ---------------- workspace layout (float offsets) ----------------
constexpr long OFF_FLAG = 0;                        // int flag at word 0
constexpr long OFF_FL   = 256;                      // feat_l f32   [8][128][4096]
constexpr long OFF_FS   = OFF_FL  + (long)Bn*Cn*HWn;      // feat_s f32 [8][128][1024]
constexpr long OFF_W1T  = OFF_FS  + (long)Bn*Cn*HWs;      // w1t [b][c][o] 8*128*128
constexpr long OFF_WOT  = OFF_W1T + (long)Bn*Cn*Cn;       // w_offT [c 256][o 128] (2x folded)
constexpr long OFF_WCT  = OFF_WOT + (long)2*Cn*Cn;        // w_cmT [c 128][k 9][oc 224]
constexpr long OFF_WDT  = OFF_WCT + (long)Cn*Kn*224;      // w_dcn bf16 [k][o][c] (reuses f32-sized slot)
constexpr long OFF_BCM  = OFF_WDT + (long)Kn*Cn*Cn;       // b_cm (216, padded 256)
constexpr long OFF_BDC  = OFF_BCM + 256;                  // b_dcn (128, padded 256)
constexpr long OFF_GAP  = OFF_BDC + 256;                  // gap [b][c]
constexpr long OFF_AT   = OFF_GAP + (long)Bn*Cn;          // 1+sigmoid(atten) [b][c]
constexpr long OFF_FUP  = OFF_AT  + (long)Bn*Cn;          // feat_up f32 [8][128][4096]
constexpr long OFF_ARM  = OFF_FUP + (long)Bn*Cn*HWn;      // feat_arm f32
constexpr long OFF_OFT  = OFF_ARM + (long)Bn*Cn*HWn;      // off_feat f32
constexpr long OFF_OM   = OFF_OFT + (long)Bn*Cn*HWn;      // om f32 [8][216][4096] (mask sigmoided)

static __device__ __forceinline__ float ldin(const void* p, long i, bool isbf) {
  if (isbf) return __bfloat162float(((const __hip_bfloat16*)p)[i]);
  return ((const float*)p)[i];
}

// f32 -> bf16 bits (RNE, finite inputs)
static __device__ __forceinline__ unsigned short f2b(float f) {
  unsigned u = __builtin_bit_cast(unsigned, f);
  u += 0x7FFFu + ((u >> 16) & 1u);
  return (unsigned short)(u >> 16);
}
static __device__ __forceinline__ unsigned pack2(float v0, float v1) {
  return ((unsigned)f2b(v1) << 16) | (unsigned)f2b(v0);
}

// ---------------- dtype detector ----------------
__global__ __launch_bounds__(256) void k_detect(const unsigned int* __restrict__ p,
                                                int* __restrict__ flag) {
  __shared__ int cnt[256];
  int t = threadIdx.x;
  int c = 0;
  for (int i = 0; i < 4; ++i) {
    unsigned v = p[t * 4 + i];
    unsigned e = (v >> 7) & 0xFFu;
    c += (e >= 118u && e <= 130u) ? 1 : 0;
  }
  cnt[t] = c;
  __syncthreads();
  for (int s = 128; s > 0; s >>= 1) {
    if (t < s) cnt[t] += cnt[t + s];
    __syncthreads();
  }
  if (t == 0) *flag = (cnt[0] > 512) ? 1 : 0;
}

// ---------------- input conversion ----------------
__global__ __launch_bounds__(256) void k_cvt(const void* __restrict__ src,
                                             float* __restrict__ dst, int n,
                                             const int* __restrict__ flag) {
  int stride = gridDim.x * blockDim.x;
  int i0 = blockIdx.x * blockDim.x + threadIdx.x;
  if (*flag) {
    const __hip_bfloat16* s = (const __hip_bfloat16*)src;
    for (int i = i0; i < n; i += stride) dst[i] = __bfloat162float(s[i]);
  } else {
    const float* s = (const float*)src;
    for (int i = i0; i < n; i += stride) dst[i] = s[i];
  }
}

// w_off [o 128][c 256] -> [c 256][o 128], with 2.0x folded for c>=128
__global__ __launch_bounds__(256) void k_woffT(const void* __restrict__ src,
                                               float* __restrict__ dst,
                                               const int* __restrict__ flag) {
  int i = blockIdx.x * 256 + threadIdx.x;
  if (i >= 2 * Cn * Cn) return;
  int c = i >> 7, o = i & 127;
  bool isbf = (*flag != 0);
  float v = ldin(src, (long)o * 256 + c, isbf);
  if (c >= Cn) v *= 2.0f;
  dst[i] = v;
}

// w_cm [oc 216][c 128][k 9] -> [c][k][oc padded to 224]
__global__ __launch_bounds__(256) void k_wcmT(const void* __restrict__ src,
                                              float* __restrict__ dst,
                                              const int* __restrict__ flag) {
  int i = blockIdx.x * 256 + threadIdx.x;
  if (i >= CMn * Cn * Kn) return;
  int oc = i / (Cn * Kn);
  int c = (i / Kn) % Cn;
  int k = i % Kn;
  bool isbf = (*flag != 0);
  dst[((long)c * Kn + k) * 224 + oc] = ldin(src, i, isbf);
}

// w_dcn [o 128][c 128][k 9] -> bf16 [k][o][c]
__global__ __launch_bounds__(256) void k_wdcnB(const void* __restrict__ src,
                                               unsigned short* __restrict__ dst,
                                               const int* __restrict__ flag) {
  int i = blockIdx.x * 256 + threadIdx.x;
  if (i >= Kn * Cn * Cn) return;
  int k = i / (Cn * Cn);
  int o = (i >> 7) & 127;
  int c = i & 127;
  bool isbf = (*flag != 0);
  float v = ldin(src, ((long)o * Cn + c) * Kn + k, isbf);
  dst[i] = f2b(v);
}

// ---------------- gap (global average pool) ----------------
__global__ __launch_bounds__(256) void k_gap(const float* __restrict__ fl,
                                             float* __restrict__ gap) {
  __shared__ float red[256];
  int bc = blockIdx.x, t = threadIdx.x;
  const float* p = fl + (long)bc * HWn;
  float s = 0.f;
  for (int i = t; i < HWn; i += 256) s += p[i];
  red[t] = s;
  __syncthreads();
  for (int k = 128; k > 0; k >>= 1) {
    if (t < k) red[t] += red[t + k];
    __syncthreads();
  }
  if (t == 0) gap[bc] = red[0] * (1.0f / HWn);
}

// ---------------- atten ----------------
__global__ __launch_bounds__(256) void k_atten(const float* __restrict__ gap,
                                               const void* __restrict__ wat,
                                               float* __restrict__ at1p,
                                               const int* __restrict__ flag) {
  int tid = blockIdx.x * 256 + threadIdx.x;
  if (tid >= Bn * Cn) return;
  int b = tid >> 7, o = tid & 127;
  bool isbf = (*flag != 0);
  const float* g = gap + b * Cn;
  float s = 0.f;
  for (int c = 0; c < Cn; ++c) s += g[c] * ldin(wat, (long)o * Cn + c, isbf);
  at1p[tid] = 1.0f + 1.0f / (1.0f + expf(-s));
}

// w1t[b][c][o] = w_fsm[o][c] * (1 + atten[b][c])
__global__ __launch_bounds__(256) void k_w1t(const void* __restrict__ wfsm,
                                             const float* __restrict__ at1p,
                                             float* __restrict__ dst,
                                             const int* __restrict__ flag) {
  int i = blockIdx.x * 256 + threadIdx.x;
  if (i >= Bn * Cn * Cn) return;
  int b = i >> 14, c = (i >> 7) & 127, o = i & 127;
  bool isbf = (*flag != 0);
  dst[i] = ldin(wfsm, (long)o * Cn + c, isbf) * at1p[b * Cn + c];
}

// ---------------- bilinear 2x upsample ----------------
__global__ __launch_bounds__(256) void k_up(const float* __restrict__ fs,
                                            float* __restrict__ fup) {
  int idx = blockIdx.x * 256 + threadIdx.x;
  if (idx >= Bn * Cn * HWn) return;
  int w = idx & 63, h = (idx >> 6) & 63, bc = idx >> 12;
  const float* s = fs + (long)bc * HWs;
  int iy0; float fy;
  if (h & 1) { iy0 = (h - 1) >> 1; fy = 0.25f; } else { iy0 = (h >> 1) - 1; fy = 0.75f; }
  int ix0; float fx;
  if (w & 1) { ix0 = (w - 1) >> 1; fx = 0.25f; } else { ix0 = (w >> 1) - 1; fx = 0.75f; }
  int iy1 = min(iy0 + 1, Hs - 1); iy0 = max(iy0, 0);
  int ix1 = min(ix0 + 1, Ws - 1); ix0 = max(ix0, 0);
  float v = (1.f - fy) * ((1.f - fx) * s[iy0 * Ws + ix0] + fx * s[iy0 * Ws + ix1]) +
            fy        * ((1.f - fx) * s[iy1 * Ws + ix0] + fx * s[iy1 * Ws + ix1]);
  fup[idx] = v;
}

// ---------------- feat_arm ----------------
__global__ __launch_bounds__(256) void k_farm(const float* __restrict__ fl,
                                              const float* __restrict__ w1t,
                                              float* __restrict__ farm) {
  const int t = threadIdx.x;
  const int b = blockIdx.z, og = blockIdx.y;
  const int pos = blockIdx.x * 256 + t;
  const float* x = fl + (long)b * Cn * HWn + pos;
  const float* wb = w1t + (long)b * Cn * Cn + og * 8;
  float acc[8];
#pragma unroll
  for (int o = 0; o < 8; ++o) acc[o] = 0.f;
  for (int c = 0; c < Cn; ++c) {
    float xv = x[(long)c * HWn];
    const float4* w4 = (const float4*)(wb + (long)c * Cn);
    float4 wa = w4[0], wc = w4[1];
    acc[0] += xv * wa.x; acc[1] += xv * wa.y; acc[2] += xv * wa.z; acc[3] += xv * wa.w;
    acc[4] += xv * wc.x; acc[5] += xv * wc.y; acc[6] += xv * wc.z; acc[7] += xv * wc.w;
  }
#pragma unroll
  for (int o = 0; o < 8; ++o)
    farm[(long)(b * Cn + og * 8 + o) * HWn + pos] = acc[o];
}

// ---------------- off_feat ----------------
__global__ __launch_bounds__(256) void k_offf(const float* __restrict__ arm,
                                              const float* __restrict__ fup,
                                              const float* __restrict__ wot,
                                              float* __restrict__ oft) {
  const int t = threadIdx.x;
  const int b = blockIdx.z, og = blockIdx.y;
  const int pos = blockIdx.x * 256 + t;
  const float* xa = arm + (long)b * Cn * HWn + pos;
  const float* xu = fup + (long)b * Cn * HWn + pos;
  const float* wg = wot + og * 8;
  float acc[8];
#pragma unroll
  for (int o = 0; o < 8; ++o) acc[o] = 0.f;
  for (int c = 0; c < Cn; ++c) {
    float xv = xa[(long)c * HWn];
    const float4* w4 = (const float4*)(wg + (long)c * Cn);
    float4 wa = w4[0], wc = w4[1];
    acc[0] += xv * wa.x; acc[1] += xv * wa.y; acc[2] += xv * wa.z; acc[3] += xv * wa.w;
    acc[4] += xv * wc.x; acc[5] += xv * wc.y; acc[6] += xv * wc.z; acc[7] += xv * wc.w;
  }
  for (int c = 0; c < Cn; ++c) {
    float xv = xu[(long)c * HWn];
    const float4* w4 = (const float4*)(wg + (long)(Cn + c) * Cn);
    float4 wa = w4[0], wc = w4[1];
    acc[0] += xv * wa.x; acc[1] += xv * wa.y; acc[2] += xv * wa.z; acc[3] += xv * wa.w;
    acc[4] += xv * wc.x; acc[5] += xv * wc.y; acc[6] += xv * wc.z; acc[7] += xv * wc.w;
  }
#pragma unroll
  for (int o = 0; o < 8; ++o)
    oft[(long)(b * Cn + og * 8 + o) * HWn + pos] = acc[o];
}

// ---------------- 3x3 conv -> om ----------------
__global__ __launch_bounds__(256) void k_convcm(const float* __restrict__ xin,
                                                const float* __restrict__ wcmT,
                                                const float* __restrict__ bcm,
                                                float* __restrict__ om) {
  __shared__ float xs[8][34][34];
  const int b = blockIdx.z, ocg = blockIdx.y, tile = blockIdx.x, t = threadIdx.x;
  const int ty0 = (tile >> 1) * 32, tx0 = (tile & 1) * 32;
  const int qx = t & 15, qy = t >> 4;
  float acc[8][2][2];
#pragma unroll
  for (int oc = 0; oc < 8; ++oc)
    for (int a = 0; a < 2; ++a)
      for (int d = 0; d < 2; ++d) acc[oc][a][d] = 0.f;

  for (int cc = 0; cc < 16; ++cc) {
    for (int i = t; i < 8 * 34 * 34; i += 256) {
      int c = i / 1156, rem = i % 1156, r = rem / 34, col = rem % 34;
      int gy = ty0 + r - 1, gx = tx0 + col - 1;
      float v = 0.f;
      if (gy >= 0 && gy < Hn && gx >= 0 && gx < Wn)
        v = xin[(long)(b * Cn + cc * 8 + c) * HWn + gy * Wn + gx];
      xs[c][r][col] = v;
    }
    __syncthreads();
    for (int c = 0; c < 8; ++c) {
      float xv[4][4];
#pragma unroll
      for (int r = 0; r < 4; ++r)
#pragma unroll
        for (int cl = 0; cl < 4; ++cl) xv[r][cl] = xs[c][2 * qy + r][2 * qx + cl];
      const float* wrow = wcmT + ((long)(cc * 8 + c) * Kn) * 224 + ocg * 8;
#pragma unroll
      for (int ky = 0; ky < 3; ++ky)
#pragma unroll
        for (int kx = 0; kx < 3; ++kx) {
          const float4* w4 = (const float4*)(wrow + (long)(ky * 3 + kx) * 224);
          float4 wa = w4[0], wc = w4[1];
          float wv[8] = {wa.x, wa.y, wa.z, wa.w, wc.x, wc.y, wc.z, wc.w};
#pragma unroll
          for (int oc = 0; oc < 8; ++oc) {
            acc[oc][0][0] += xv[ky][kx] * wv[oc];
            acc[oc][0][1] += xv[ky][kx + 1] * wv[oc];
            acc[oc][1][0] += xv[ky + 1][kx] * wv[oc];
            acc[oc][1][1] += xv[ky + 1][kx + 1] * wv[oc];
          }
        }
    }
    __syncthreads();
  }
#pragma unroll
  for (int oc = 0; oc < 8; ++oc) {
    int ch = ocg * 8 + oc;
    float bias = bcm[ch];
#pragma unroll
    for (int py = 0; py < 2; ++py)
#pragma unroll
      for (int px = 0; px < 2; ++px) {
        int gy = ty0 + 2 * qy + py, gx = tx0 + 2 * qx + px;
        float v = acc[oc][py][px] + bias;
        if (ch >= 144) v = 1.0f / (1.0f + expf(-v));
        om[(long)(b * CMn + ch) * HWn + gy * Wn + gx] = v;
      }
  }
}

// ---------------- fused DCN v2 via bf16 MFMA ----------------
// Block: (h, b, w-half). 256 threads = 4 waves.
// Gather: thread (w = w0+(t&31), g = t>>5) bilinear-samples its group's 16
// channels, packs bf16 pairs into XOR-swizzled LDS val[w 32][c 128].
// MFMA: wave wid owns o-range [wid*32, wid*32+32): A-frag from val (m=w),
// B-frag 16B global loads from wdb [k][o][c] bf16; acc f32.
__global__ __launch_bounds__(256) void k_dcn(const float* __restrict__ om,
                                             const float* __restrict__ fup,
                                             const unsigned short* __restrict__ wdb,
                                             const float* __restrict__ bdc,
                                             const float* __restrict__ farm,
                                             void* __restrict__ out,
                                             const int* __restrict__ flagp) {
  __shared__ unsigned int val[2048];     // [w 32][cpair 64] u32, swizzled, 8KB
  const int h = blockIdx.x, b = blockIdx.y, w0 = blockIdx.z * 32;
  const int t = threadIdx.x;
  const int lane = t & 63, wid = t >> 6;
  const int gw = t & 31, g = t >> 5;     // gather role: w-lane, deform group
  f32x4 acc[2][2];
#pragma unroll
  for (int mt = 0; mt < 2; ++mt)
#pragma unroll
    for (int nt = 0; nt < 2; ++nt) acc[mt][nt] = (f32x4){0.f, 0.f, 0.f, 0.f};

  const float* omb = om + (long)b * CMn * HWn + h * Wn;
  const float* fupb = fup + (long)b * Cn * HWn;
  const int wcol = w0 + gw;

  for (int k = 0; k < Kn; ++k) {
    // ---- phase A: bilinear setup for (g, wcol), this tap ----
    int ch = g * Kn + k;
    float oy = omb[(long)ch * HWn + wcol];
    float ox = omb[(long)(72 + ch) * HWn + wcol];
    float mk = omb[(long)(144 + ch) * HWn + wcol];
    float py = (float)(h + k / 3 - 1) + oy;
    float px = (float)(wcol + k % 3 - 1) + ox;
    float fy = floorf(py), fx = floorf(px);
    float ly = py - fy, lx = px - fx;
    int y0 = (int)fy, x0 = (int)fx, y1 = y0 + 1, x1 = x0 + 1;
    float vy0 = (y0 >= 0 && y0 < Hn) ? 1.f : 0.f;
    float vy1 = (y1 >= 0 && y1 < Hn) ? 1.f : 0.f;
    float vx0 = (x0 >= 0 && x0 < Wn) ? 1.f : 0.f;
    float vx1 = (x1 >= 0 && x1 < Wn) ? 1.f : 0.f;
    int cy0 = min(max(y0, 0), Hn - 1), cy1 = min(max(y1, 0), Hn - 1);
    int cx0 = min(max(x0, 0), Wn - 1), cx1 = min(max(x1, 0), Wn - 1);
    float wq0 = (1.f - ly) * (1.f - lx) * vy0 * vx0 * mk;
    float wq1 = (1.f - ly) * lx * vy0 * vx1 * mk;
    float wq2 = ly * (1.f - lx) * vy1 * vx0 * mk;
    float wq3 = ly * lx * vy1 * vx1 * mk;
    const float* p0 = fupb + (long)(g * 16) * HWn + (cy0 * Wn + cx0);
    const float* p1 = fupb + (long)(g * 16) * HWn + (cy0 * Wn + cx1);
    const float* p2 = fupb + (long)(g * 16) * HWn + (cy1 * Wn + cx0);
    const float* p3 = fupb + (long)(g * 16) * HWn + (cy1 * Wn + cx1);
    // ---- gather: 16 channels of this group -> 8 packed LDS writes ----
#pragma unroll
    for (int j = 0; j < 8; ++j) {
      float v0 = wq0 * p0[0] + wq1 * p1[0] + wq2 * p2[0] + wq3 * p3[0];
      float v1 = wq0 * p0[HWn] + wq1 * p1[HWn] + wq2 * p2[HWn] + wq3 * p3[HWn];
      int c = g * 16 + j * 2;
      int lin = gw * 256 + c * 2;                 // byte offset, row = 256B
      val[(lin ^ ((gw & 7) << 4)) >> 2] = pack2(v0, v1);
      p0 += 2 * HWn; p1 += 2 * HWn; p2 += 2 * HWn; p3 += 2 * HWn;
    }
    __syncthreads();
    // ---- MFMA: acc[mt][nt] += val[w][c] * wdb[k][o][c] ----
    const unsigned short* wkb = wdb + (long)k * Cn * Cn;
#pragma unroll
    for (int ks = 0; ks < 4; ++ks) {
      int c0 = ks * 32 + 8 * (lane >> 4);
      bf16x8 af[2], bfv[2];
#pragma unroll
      for (int mt = 0; mt < 2; ++mt) {
        int lw = mt * 16 + (lane & 15);
        int lin = lw * 256 + c0 * 2;
        af[mt] = *(const bf16x8*)((const char*)val + (lin ^ ((lw & 7) << 4)));
      }
#pragma unroll
      for (int nt = 0; nt < 2; ++nt) {
        int o = wid * 32 + nt * 16 + (lane & 15);
        bfv[nt] = *(const bf16x8*)(wkb + (long)o * Cn + c0);
      }
#pragma unroll
      for (int mt = 0; mt < 2; ++mt)
#pragma unroll
        for (int nt = 0; nt < 2; ++nt)
          acc[mt][nt] = __builtin_amdgcn_mfma_f32_16x16x32_bf16(
              af[mt], bfv[nt], acc[mt][nt], 0, 0, 0);
    }
    __syncthreads();
  }

  // ---- epilogue: bias, relu, + feat_arm, dtype-branched store ----
  bool isbf = (*flagp != 0);
#pragma unroll
  for (int nt = 0; nt < 2; ++nt) {
    int o = wid * 32 + nt * 16 + (lane & 15);
    float bias = bdc[o];
#pragma unroll
    for (int mt = 0; mt < 2; ++mt) {
#pragma unroll
      for (int r = 0; r < 4; ++r) {
        int w = w0 + mt * 16 + (lane >> 4) * 4 + r;
        long oi = (long)(b * Cn + o) * HWn + h * Wn + w;
        float v = acc[mt][nt][r] + bias;
        v = fmaxf(v, 0.f) + farm[oi];
        if (isbf) ((__hip_bfloat16*)out)[oi] = __float2bfloat16(v);
        else      ((float*)out)[oi] = v;
      }
    }
  }
}

// ---------------- launcher ----------------
extern "C" void kernel_launch(void* const* d_in, const int* in_sizes, int n_in,
                              void* d_out, int out_size, void* d_ws, size_t ws_size,
                              hipStream_t stream) {
  (void)in_sizes; (void)n_in; (void)out_size; (void)ws_size;
  const void* feat_l  = d_in[0];
  const void* feat_s  = d_in[1];
  const void* w_atten = d_in[2];
  const void* w_fsm   = d_in[3];
  const void* w_off   = d_in[4];
  const void* w_cm    = d_in[5];
  const void* b_cm    = d_in[6];
  const void* w_dcn   = d_in[7];
  const void* b_dcn   = d_in[8];
  float* ws = (float*)d_ws;
  int* flagw = (int*)d_ws;
  const int* flag = (const int*)d_ws;
  unsigned short* wdb = (unsigned short*)(ws + OFF_WDT);

  k_detect<<<1, 256, 0, stream>>>((const unsigned int*)feat_l, flagw);
  k_cvt<<<2048, 256, 0, stream>>>(feat_l, ws + OFF_FL, Bn * Cn * HWn, flag);
  k_cvt<<<512, 256, 0, stream>>>(feat_s, ws + OFF_FS, Bn * Cn * HWs, flag);
  k_cvt<<<1, 256, 0, stream>>>(b_cm, ws + OFF_BCM, CMn, flag);
  k_cvt<<<1, 256, 0, stream>>>(b_dcn, ws + OFF_BDC, Cn, flag);
  k_woffT<<<(2 * Cn * Cn + 255) / 256, 256, 0, stream>>>(w_off, ws + OFF_WOT, flag);
  k_wcmT<<<(CMn * Cn * Kn + 255) / 256, 256, 0, stream>>>(w_cm, ws + OFF_WCT, flag);
  k_wdcnB<<<(Kn * Cn * Cn + 255) / 256, 256, 0, stream>>>(w_dcn, wdb, flag);
  k_gap<<<Bn * Cn, 256, 0, stream>>>(ws + OFF_FL, ws + OFF_GAP);
  k_atten<<<4, 256, 0, stream>>>(ws + OFF_GAP, w_atten, ws + OFF_AT, flag);
  k_w1t<<<(Bn * Cn * Cn + 255) / 256, 256, 0, stream>>>(w_fsm, ws + OFF_AT, ws + OFF_W1T, flag);
  k_up<<<(Bn * Cn * HWn + 255) / 256, 256, 0, stream>>>(ws + OFF_FS, ws + OFF_FUP);
  k_farm<<<dim3(16, 16, 8), 256, 0, stream>>>(ws + OFF_FL, ws + OFF_W1T, ws + OFF_ARM);
  k_offf<<<dim3(16, 16, 8), 256, 0, stream>>>(ws + OFF_ARM, ws + OFF_FUP, ws + OFF_WOT, ws + OFF_OFT);
  k_convcm<<<dim3(4, 27, 8), 256, 0, stream>>>(ws + OFF_OFT, ws + OFF_WCT, ws + OFF_BCM, ws + OFF_OM);
  k_dcn<<<dim3(64, 8, 2), 256, 0, stream>>>(ws + OFF_OM, ws + OFF_FUP, wdb,
                                            ws + OFF_BDC, ws + OFF_ARM, d_out, flag);
}

// Round 3
// 428.394 us; speedup vs baseline: 2.5216x; 1.5278x over previous
//
#include <hip/hip_runtime.h>
#include <hip/hip_bf16.h>

// ---------------- problem constants ----------------
constexpr int Bn = 8, Cn = 128, Hn = 64, Wn = 64, HWn = Hn * Wn;
constexpr int DGn = 8, Kn = 9, CMn = 216;          // CM = DG*3*K
constexpr int Hs = 32, Ws = 32, HWs = Hs * Ws;

typedef __attribute__((ext_vector_type(8))) short bf16x8;
typedef __attribute__((ext_vector_type(4))) float f32x4;

// ---------------- workspace layout (float offsets) ----------------
constexpr long OFF_FLAG = 0;                        // int flag at word 0
constexpr long OFF_FL   = 256;                      // feat_l f32   [8][128][4096]
constexpr long OFF_FS   = OFF_FL  + (long)Bn*Cn*HWn;      // feat_s f32 [8][128][1024]
constexpr long OFF_W1T  = OFF_FS  + (long)Bn*Cn*HWs;      // w1t [b][c][o] 8*128*128
constexpr long OFF_WOT  = OFF_W1T + (long)Bn*Cn*Cn;       // w_offT [c 256][o 128] (2x folded)
constexpr long OFF_WCT  = OFF_WOT + (long)2*Cn*Cn;        // w_cm bf16 [9][224][128] (in f32-sized slot)
constexpr long OFF_WDT  = OFF_WCT + (long)Cn*Kn*224;      // w_dcn bf16 [k][o][c]
constexpr long OFF_BCM  = OFF_WDT + (long)Kn*Cn*Cn;       // b_cm (216, padded 256)
constexpr long OFF_BDC  = OFF_BCM + 256;                  // b_dcn (128, padded 256)
constexpr long OFF_GAP  = OFF_BDC + 256;                  // gap [b][c]
constexpr long OFF_AT   = OFF_GAP + (long)Bn*Cn;          // 1+sigmoid(atten) [b][c]
constexpr long OFF_FUP  = OFF_AT  + (long)Bn*Cn;          // feat_up f32 [8][128][4096]
constexpr long OFF_ARM  = OFF_FUP + (long)Bn*Cn*HWn;      // feat_arm f32
constexpr long OFF_OFT  = OFF_ARM + (long)Bn*Cn*HWn;      // off_feat bf16 NHWC [8][4096][128]
constexpr long OFF_OM   = OFF_OFT + (long)Bn*Cn*HWn;      // om f32 [8][216][4096] (mask sigmoided)

static __device__ __forceinline__ float ldin(const void* p, long i, bool isbf) {
  if (isbf) return __bfloat162float(((const __hip_bfloat16*)p)[i]);
  return ((const float*)p)[i];
}

// f32 -> bf16 bits (RNE, finite inputs)
static __device__ __forceinline__ unsigned short f2b(float f) {
  unsigned u = __builtin_bit_cast(unsigned, f);
  u += 0x7FFFu + ((u >> 16) & 1u);
  return (unsigned short)(u >> 16);
}
static __device__ __forceinline__ unsigned pack2(float v0, float v1) {
  return ((unsigned)f2b(v1) << 16) | (unsigned)f2b(v0);
}

// ---------------- dtype detector ----------------
__global__ __launch_bounds__(256) void k_detect(const unsigned int* __restrict__ p,
                                                int* __restrict__ flag) {
  __shared__ int cnt[256];
  int t = threadIdx.x;
  int c = 0;
  for (int i = 0; i < 4; ++i) {
    unsigned v = p[t * 4 + i];
    unsigned e = (v >> 7) & 0xFFu;
    c += (e >= 118u && e <= 130u) ? 1 : 0;
  }
  cnt[t] = c;
  __syncthreads();
  for (int s = 128; s > 0; s >>= 1) {
    if (t < s) cnt[t] += cnt[t + s];
    __syncthreads();
  }
  if (t == 0) *flag = (cnt[0] > 512) ? 1 : 0;
}

// ---------------- input conversion ----------------
__global__ __launch_bounds__(256) void k_cvt(const void* __restrict__ src,
                                             float* __restrict__ dst, int n,
                                             const int* __restrict__ flag) {
  int stride = gridDim.x * blockDim.x;
  int i0 = blockIdx.x * blockDim.x + threadIdx.x;
  if (*flag) {
    const __hip_bfloat16* s = (const __hip_bfloat16*)src;
    for (int i = i0; i < n; i += stride) dst[i] = __bfloat162float(s[i]);
  } else {
    const float* s = (const float*)src;
    for (int i = i0; i < n; i += stride) dst[i] = s[i];
  }
}

// w_off [o 128][c 256] -> [c 256][o 128], with 2.0x folded for c>=128
__global__ __launch_bounds__(256) void k_woffT(const void* __restrict__ src,
                                               float* __restrict__ dst,
                                               const int* __restrict__ flag) {
  int i = blockIdx.x * 256 + threadIdx.x;
  if (i >= 2 * Cn * Cn) return;
  int c = i >> 7, o = i & 127;
  bool isbf = (*flag != 0);
  float v = ldin(src, (long)o * 256 + c, isbf);
  if (c >= Cn) v *= 2.0f;
  dst[i] = v;
}

// w_cm [oc 216][c 128][k 9] -> bf16 [tap 9][oc 224 (zero-pad)][c 128]
__global__ __launch_bounds__(256) void k_wcmB(const void* __restrict__ src,
                                              unsigned short* __restrict__ dst,
                                              const int* __restrict__ flag) {
  int i = blockIdx.x * 256 + threadIdx.x;
  if (i >= Kn * 224 * Cn) return;
  int tap = i / (224 * Cn);
  int oc = (i >> 7) % 224;
  int c = i & 127;
  bool isbf = (*flag != 0);
  float v = 0.f;
  if (oc < CMn) v = ldin(src, ((long)oc * Cn + c) * Kn + tap, isbf);
  dst[i] = f2b(v);
}

// w_dcn [o 128][c 128][k 9] -> bf16 [k][o][c]
__global__ __launch_bounds__(256) void k_wdcnB(const void* __restrict__ src,
                                               unsigned short* __restrict__ dst,
                                               const int* __restrict__ flag) {
  int i = blockIdx.x * 256 + threadIdx.x;
  if (i >= Kn * Cn * Cn) return;
  int k = i / (Cn * Cn);
  int o = (i >> 7) & 127;
  int c = i & 127;
  bool isbf = (*flag != 0);
  float v = ldin(src, ((long)o * Cn + c) * Kn + k, isbf);
  dst[i] = f2b(v);
}

// ---------------- gap ----------------
__global__ __launch_bounds__(256) void k_gap(const float* __restrict__ fl,
                                             float* __restrict__ gap) {
  __shared__ float red[256];
  int bc = blockIdx.x, t = threadIdx.x;
  const float* p = fl + (long)bc * HWn;
  float s = 0.f;
  for (int i = t; i < HWn; i += 256) s += p[i];
  red[t] = s;
  __syncthreads();
  for (int k = 128; k > 0; k >>= 1) {
    if (t < k) red[t] += red[t + k];
    __syncthreads();
  }
  if (t == 0) gap[bc] = red[0] * (1.0f / HWn);
}

// ---------------- atten ----------------
__global__ __launch_bounds__(256) void k_atten(const float* __restrict__ gap,
                                               const void* __restrict__ wat,
                                               float* __restrict__ at1p,
                                               const int* __restrict__ flag) {
  int tid = blockIdx.x * 256 + threadIdx.x;
  if (tid >= Bn * Cn) return;
  int b = tid >> 7, o = tid & 127;
  bool isbf = (*flag != 0);
  const float* g = gap + b * Cn;
  float s = 0.f;
  for (int c = 0; c < Cn; ++c) s += g[c] * ldin(wat, (long)o * Cn + c, isbf);
  at1p[tid] = 1.0f + 1.0f / (1.0f + expf(-s));
}

// w1t[b][c][o] = w_fsm[o][c] * (1 + atten[b][c])
__global__ __launch_bounds__(256) void k_w1t(const void* __restrict__ wfsm,
                                             const float* __restrict__ at1p,
                                             float* __restrict__ dst,
                                             const int* __restrict__ flag) {
  int i = blockIdx.x * 256 + threadIdx.x;
  if (i >= Bn * Cn * Cn) return;
  int b = i >> 14, c = (i >> 7) & 127, o = i & 127;
  bool isbf = (*flag != 0);
  dst[i] = ldin(wfsm, (long)o * Cn + c, isbf) * at1p[b * Cn + c];
}

// ---------------- bilinear 2x upsample ----------------
__global__ __launch_bounds__(256) void k_up(const float* __restrict__ fs,
                                            float* __restrict__ fup) {
  int idx = blockIdx.x * 256 + threadIdx.x;
  if (idx >= Bn * Cn * HWn) return;
  int w = idx & 63, h = (idx >> 6) & 63, bc = idx >> 12;
  const float* s = fs + (long)bc * HWs;
  int iy0; float fy;
  if (h & 1) { iy0 = (h - 1) >> 1; fy = 0.25f; } else { iy0 = (h >> 1) - 1; fy = 0.75f; }
  int ix0; float fx;
  if (w & 1) { ix0 = (w - 1) >> 1; fx = 0.25f; } else { ix0 = (w >> 1) - 1; fx = 0.75f; }
  int iy1 = min(iy0 + 1, Hs - 1); iy0 = max(iy0, 0);
  int ix1 = min(ix0 + 1, Ws - 1); ix0 = max(ix0, 0);
  float v = (1.f - fy) * ((1.f - fx) * s[iy0 * Ws + ix0] + fx * s[iy0 * Ws + ix1]) +
            fy        * ((1.f - fx) * s[iy1 * Ws + ix0] + fx * s[iy1 * Ws + ix1]);
  fup[idx] = v;
}

// ---------------- feat_arm ----------------
__global__ __launch_bounds__(256) void k_farm(const float* __restrict__ fl,
                                              const float* __restrict__ w1t,
                                              float* __restrict__ farm) {
  const int t = threadIdx.x;
  const int b = blockIdx.z, og = blockIdx.y;
  const int pos = blockIdx.x * 256 + t;
  const float* x = fl + (long)b * Cn * HWn + pos;
  const float* wb = w1t + (long)b * Cn * Cn + og * 8;
  float acc[8];
#pragma unroll
  for (int o = 0; o < 8; ++o) acc[o] = 0.f;
  for (int c = 0; c < Cn; ++c) {
    float xv = x[(long)c * HWn];
    const float4* w4 = (const float4*)(wb + (long)c * Cn);
    float4 wa = w4[0], wc = w4[1];
    acc[0] += xv * wa.x; acc[1] += xv * wa.y; acc[2] += xv * wa.z; acc[3] += xv * wa.w;
    acc[4] += xv * wc.x; acc[5] += xv * wc.y; acc[6] += xv * wc.z; acc[7] += xv * wc.w;
  }
#pragma unroll
  for (int o = 0; o < 8; ++o)
    farm[(long)(b * Cn + og * 8 + o) * HWn + pos] = acc[o];
}

// ---------------- off_feat -> bf16 NHWC [b][pos][c] ----------------
__global__ __launch_bounds__(256) void k_offf(const float* __restrict__ arm,
                                              const float* __restrict__ fup,
                                              const float* __restrict__ wot,
                                              unsigned short* __restrict__ oftb) {
  const int t = threadIdx.x;
  const int b = blockIdx.z, og = blockIdx.y;
  const int pos = blockIdx.x * 256 + t;
  const float* xa = arm + (long)b * Cn * HWn + pos;
  const float* xu = fup + (long)b * Cn * HWn + pos;
  const float* wg = wot + og * 8;
  float acc[8];
#pragma unroll
  for (int o = 0; o < 8; ++o) acc[o] = 0.f;
  for (int c = 0; c < Cn; ++c) {
    float xv = xa[(long)c * HWn];
    const float4* w4 = (const float4*)(wg + (long)c * Cn);
    float4 wa = w4[0], wc = w4[1];
    acc[0] += xv * wa.x; acc[1] += xv * wa.y; acc[2] += xv * wa.z; acc[3] += xv * wa.w;
    acc[4] += xv * wc.x; acc[5] += xv * wc.y; acc[6] += xv * wc.z; acc[7] += xv * wc.w;
  }
  for (int c = 0; c < Cn; ++c) {
    float xv = xu[(long)c * HWn];
    const float4* w4 = (const float4*)(wg + (long)(Cn + c) * Cn);
    float4 wa = w4[0], wc = w4[1];
    acc[0] += xv * wa.x; acc[1] += xv * wa.y; acc[2] += xv * wa.z; acc[3] += xv * wa.w;
    acc[4] += xv * wc.x; acc[5] += xv * wc.y; acc[6] += xv * wc.z; acc[7] += xv * wc.w;
  }
  uint4 pk;
  pk.x = pack2(acc[0], acc[1]); pk.y = pack2(acc[2], acc[3]);
  pk.z = pack2(acc[4], acc[5]); pk.w = pack2(acc[6], acc[7]);
  *(uint4*)(oftb + (((long)b * HWn + pos) << 7) + og * 8) = pk;
}

// ---------------- 3x3 conv via bf16 MFMA -> om ----------------
// Block = one (h, b) output row: M=64 (w), N=224 (oc padded), K=1152.
// Stage rows h-1..h+1 x 66 cols x 128ch bf16 into XOR-swizzled LDS (49.5KB).
// 4 waves, wave wid owns w range [wid*16, wid*16+16).
__global__ __launch_bounds__(256) void k_convcm(const unsigned short* __restrict__ xb,
                                                const unsigned short* __restrict__ wb,
                                                const float* __restrict__ bcm,
                                                float* __restrict__ om) {
  __shared__ unsigned int lds[12672];   // 3*66 rows x 256B
  const int h = blockIdx.x, b = blockIdx.y;
  const int t = threadIdx.x, lane = t & 63, wid = t >> 6;
  const int m0 = wid * 16, lm = lane & 15, lh = lane >> 4;

  for (int i = t; i < 3168; i += 256) {
    int pair = i >> 4, chunk = i & 15;
    int row = pair / 66, col = pair % 66;
    int gy = h + row - 1, gx = col - 1;
    uint4 v = {0u, 0u, 0u, 0u};
    if (gy >= 0 && gy < Hn && gx >= 0 && gx < Wn)
      v = *(const uint4*)(xb + (((long)b * HWn + gy * Wn + gx) << 7) + chunk * 8);
    int byte = (pair << 8) + ((chunk << 4) ^ ((col & 7) << 4));
    *(uint4*)((char*)lds + byte) = v;
  }
  __syncthreads();

  f32x4 acc[14];
#pragma unroll
  for (int nt = 0; nt < 14; ++nt) acc[nt] = (f32x4){0.f, 0.f, 0.f, 0.f};

#pragma unroll
  for (int tap = 0; tap < 9; ++tap) {
    const int ky = tap / 3, kx = tap % 3;
    const unsigned short* wt = wb + (long)tap * 224 * Cn + lm * Cn;
    const int colA = m0 + lm + kx;                  // 0..65
    const int rowbase = (ky * 66 + colA) << 8;
#pragma unroll
    for (int ks = 0; ks < 4; ++ks) {
      int c0 = ks * 32 + lh * 8;
      bf16x8 af = *(const bf16x8*)((const char*)lds +
                    (rowbase + ((c0 << 1) ^ ((colA & 7) << 4))));
#pragma unroll
      for (int nt = 0; nt < 14; ++nt) {
        bf16x8 bfv = *(const bf16x8*)(wt + (long)nt * 16 * Cn + c0);
        acc[nt] = __builtin_amdgcn_mfma_f32_16x16x32_bf16(af, bfv, acc[nt], 0, 0, 0);
      }
    }
  }

#pragma unroll
  for (int nt = 0; nt < 14; ++nt) {
    int ch = nt * 16 + lm;
    if (ch >= CMn) continue;
    float bias = bcm[ch];
#pragma unroll
    for (int r = 0; r < 4; ++r) {
      int w = m0 + lh * 4 + r;
      float v = acc[nt][r] + bias;
      if (ch >= 144) v = 1.0f / (1.0f + expf(-v));
      om[(((long)(b * CMn + ch)) << 12) + h * Wn + w] = v;
    }
  }
}

// ---------------- fused DCN v2 via bf16 MFMA ----------------
__global__ __launch_bounds__(256) void k_dcn(const float* __restrict__ om,
                                             const float* __restrict__ fup,
                                             const unsigned short* __restrict__ wdb,
                                             const float* __restrict__ bdc,
                                             const float* __restrict__ farm,
                                             void* __restrict__ out,
                                             const int* __restrict__ flagp) {
  __shared__ unsigned int val[2048];     // [w 32][cpair 64] u32, swizzled, 8KB
  const int h = blockIdx.x, b = blockIdx.y, w0 = blockIdx.z * 32;
  const int t = threadIdx.x;
  const int lane = t & 63, wid = t >> 6;
  const int gw = t & 31, g = t >> 5;
  f32x4 acc[2][2];
#pragma unroll
  for (int mt = 0; mt < 2; ++mt)
#pragma unroll
    for (int nt = 0; nt < 2; ++nt) acc[mt][nt] = (f32x4){0.f, 0.f, 0.f, 0.f};

  const float* omb = om + (long)b * CMn * HWn + h * Wn;
  const float* fupb = fup + (long)b * Cn * HWn;
  const int wcol = w0 + gw;

  for (int k = 0; k < Kn; ++k) {
    int ch = g * Kn + k;
    float oy = omb[(long)ch * HWn + wcol];
    float ox = omb[(long)(72 + ch) * HWn + wcol];
    float mk = omb[(long)(144 + ch) * HWn + wcol];
    float py = (float)(h + k / 3 - 1) + oy;
    float px = (float)(wcol + k % 3 - 1) + ox;
    float fy = floorf(py), fx = floorf(px);
    float ly = py - fy, lx = px - fx;
    int y0 = (int)fy, x0 = (int)fx, y1 = y0 + 1, x1 = x0 + 1;
    float vy0 = (y0 >= 0 && y0 < Hn) ? 1.f : 0.f;
    float vy1 = (y1 >= 0 && y1 < Hn) ? 1.f : 0.f;
    float vx0 = (x0 >= 0 && x0 < Wn) ? 1.f : 0.f;
    float vx1 = (x1 >= 0 && x1 < Wn) ? 1.f : 0.f;
    int cy0 = min(max(y0, 0), Hn - 1), cy1 = min(max(y1, 0), Hn - 1);
    int cx0 = min(max(x0, 0), Wn - 1), cx1 = min(max(x1, 0), Wn - 1);
    float wq0 = (1.f - ly) * (1.f - lx) * vy0 * vx0 * mk;
    float wq1 = (1.f - ly) * lx * vy0 * vx1 * mk;
    float wq2 = ly * (1.f - lx) * vy1 * vx0 * mk;
    float wq3 = ly * lx * vy1 * vx1 * mk;
    const float* p0 = fupb + (long)(g * 16) * HWn + (cy0 * Wn + cx0);
    const float* p1 = fupb + (long)(g * 16) * HWn + (cy0 * Wn + cx1);
    const float* p2 = fupb + (long)(g * 16) * HWn + (cy1 * Wn + cx0);
    const float* p3 = fupb + (long)(g * 16) * HWn + (cy1 * Wn + cx1);
#pragma unroll
    for (int j = 0; j < 8; ++j) {
      float v0 = wq0 * p0[0] + wq1 * p1[0] + wq2 * p2[0] + wq3 * p3[0];
      float v1 = wq0 * p0[HWn] + wq1 * p1[HWn] + wq2 * p2[HWn] + wq3 * p3[HWn];
      int c = g * 16 + j * 2;
      int lin = gw * 256 + c * 2;
      val[(lin ^ ((gw & 7) << 4)) >> 2] = pack2(v0, v1);
      p0 += 2 * HWn; p1 += 2 * HWn; p2 += 2 * HWn; p3 += 2 * HWn;
    }
    __syncthreads();
    const unsigned short* wkb = wdb + (long)k * Cn * Cn;
#pragma unroll
    for (int ks = 0; ks < 4; ++ks) {
      int c0 = ks * 32 + 8 * (lane >> 4);
      bf16x8 af[2], bfv[2];
#pragma unroll
      for (int mt = 0; mt < 2; ++mt) {
        int lw = mt * 16 + (lane & 15);
        int lin = lw * 256 + c0 * 2;
        af[mt] = *(const bf16x8*)((const char*)val + (lin ^ ((lw & 7) << 4)));
      }
#pragma unroll
      for (int nt = 0; nt < 2; ++nt) {
        int o = wid * 32 + nt * 16 + (lane & 15);
        bfv[nt] = *(const bf16x8*)(wkb + (long)o * Cn + c0);
      }
#pragma unroll
      for (int mt = 0; mt < 2; ++mt)
#pragma unroll
        for (int nt = 0; nt < 2; ++nt)
          acc[mt][nt] = __builtin_amdgcn_mfma_f32_16x16x32_bf16(
              af[mt], bfv[nt], acc[mt][nt], 0, 0, 0);
    }
    __syncthreads();
  }

  bool isbf = (*flagp != 0);
#pragma unroll
  for (int nt = 0; nt < 2; ++nt) {
    int o = wid * 32 + nt * 16 + (lane & 15);
    float bias = bdc[o];
#pragma unroll
    for (int mt = 0; mt < 2; ++mt) {
#pragma unroll
      for (int r = 0; r < 4; ++r) {
        int w = w0 + mt * 16 + (lane >> 4) * 4 + r;
        long oi = (long)(b * Cn + o) * HWn + h * Wn + w;
        float v = acc[mt][nt][r] + bias;
        v = fmaxf(v, 0.f) + farm[oi];
        if (isbf) ((__hip_bfloat16*)out)[oi] = __float2bfloat16(v);
        else      ((float*)out)[oi] = v;
      }
    }
  }
}

// ---------------- launcher ----------------
extern "C" void kernel_launch(void* const* d_in, const int* in_sizes, int n_in,
                              void* d_out, int out_size, void* d_ws, size_t ws_size,
                              hipStream_t stream) {
  (void)in_sizes; (void)n_in; (void)out_size; (void)ws_size;
  const void* feat_l  = d_in[0];
  const void* feat_s  = d_in[1];
  const void* w_atten = d_in[2];
  const void* w_fsm   = d_in[3];
  const void* w_off   = d_in[4];
  const void* w_cm    = d_in[5];
  const void* b_cm    = d_in[6];
  const void* w_dcn   = d_in[7];
  const void* b_dcn   = d_in[8];
  float* ws = (float*)d_ws;
  int* flagw = (int*)d_ws;
  const int* flag = (const int*)d_ws;
  unsigned short* wdb = (unsigned short*)(ws + OFF_WDT);
  unsigned short* wcb = (unsigned short*)(ws + OFF_WCT);
  unsigned short* oftb = (unsigned short*)(ws + OFF_OFT);

  k_detect<<<1, 256, 0, stream>>>((const unsigned int*)feat_l, flagw);
  k_cvt<<<2048, 256, 0, stream>>>(feat_l, ws + OFF_FL, Bn * Cn * HWn, flag);
  k_cvt<<<512, 256, 0, stream>>>(feat_s, ws + OFF_FS, Bn * Cn * HWs, flag);
  k_cvt<<<1, 256, 0, stream>>>(b_cm, ws + OFF_BCM, CMn, flag);
  k_cvt<<<1, 256, 0, stream>>>(b_dcn, ws + OFF_BDC, Cn, flag);
  k_woffT<<<(2 * Cn * Cn + 255) / 256, 256, 0, stream>>>(w_off, ws + OFF_WOT, flag);
  k_wcmB<<<(Kn * 224 * Cn + 255) / 256, 256, 0, stream>>>(w_cm, wcb, flag);
  k_wdcnB<<<(Kn * Cn * Cn + 255) / 256, 256, 0, stream>>>(w_dcn, wdb, flag);
  k_gap<<<Bn * Cn, 256, 0, stream>>>(ws + OFF_FL, ws + OFF_GAP);
  k_atten<<<4, 256, 0, stream>>>(ws + OFF_GAP, w_atten, ws + OFF_AT, flag);
  k_w1t<<<(Bn * Cn * Cn + 255) / 256, 256, 0, stream>>>(w_fsm, ws + OFF_AT, ws + OFF_W1T, flag);
  k_up<<<(Bn * Cn * HWn + 255) / 256, 256, 0, stream>>>(ws + OFF_FS, ws + OFF_FUP);
  k_farm<<<dim3(16, 16, 8), 256, 0, stream>>>(ws + OFF_FL, ws + OFF_W1T, ws + OFF_ARM);
  k_offf<<<dim3(16, 16, 8), 256, 0, stream>>>(ws + OFF_ARM, ws + OFF_FUP, ws + OFF_WOT, oftb);
  k_convcm<<<dim3(64, 8), 256, 0, stream>>>(oftb, wcb, ws + OFF_BCM, ws + OFF_OM);
  k_dcn<<<dim3(64, 8, 2), 256, 0, stream>>>(ws + OFF_OM, ws + OFF_FUP, wdb,
                                            ws + OFF_BDC, ws + OFF_ARM, d_out, flag);
}

// Round 4
// 330.180 us; speedup vs baseline: 3.2717x; 1.2975x over previous
//
#include <hip/hip_runtime.h>
#include <hip/hip_bf16.h>

// ---------------- problem constants ----------------
constexpr int Bn = 8, Cn = 128, Hn = 64, Wn = 64, HWn = Hn * Wn;
constexpr int DGn = 8, Kn = 9, CMn = 216;          // CM = DG*3*K
constexpr int Hs = 32, Ws = 32, HWs = Hs * Ws;

typedef __attribute__((ext_vector_type(8))) short bf16x8;
typedef __attribute__((ext_vector_type(4))) float f32x4;

// ---------------- workspace layout (float offsets) ----------------
constexpr long OFF_FLAG = 0;                        // int flag at word 0
constexpr long OFF_FL   = 256;                      // feat_l f32   [8][128][4096]
constexpr long OFF_FS   = OFF_FL  + (long)Bn*Cn*HWn;      // feat_s f32 [8][128][1024]
constexpr long OFF_W1T  = OFF_FS  + (long)Bn*Cn*HWs;      // w1t [b][c][o] 8*128*128
constexpr long OFF_WOT  = OFF_W1T + (long)Bn*Cn*Cn;       // w_offT [c 256][o 128] (2x folded)
constexpr long OFF_WCT  = OFF_WOT + (long)2*Cn*Cn;        // w_cm bf16 [9][224][128]
constexpr long OFF_WDT  = OFF_WCT + (long)Cn*Kn*224;      // w_dcn bf16 [k][o][c]
constexpr long OFF_BCM  = OFF_WDT + (long)Kn*Cn*Cn;       // b_cm (216, padded 256)
constexpr long OFF_BDC  = OFF_BCM + 256;                  // b_dcn (128, padded 256)
constexpr long OFF_GAP  = OFF_BDC + 256;                  // gap [b][c]
constexpr long OFF_AT   = OFF_GAP + (long)Bn*Cn;          // 1+sigmoid(atten) [b][c]
constexpr long OFF_FUP  = OFF_AT  + (long)Bn*Cn;          // feat_up f32 [8][128][4096]
constexpr long OFF_ARM  = OFF_FUP + (long)Bn*Cn*HWn;      // feat_arm f32
constexpr long OFF_OFT  = OFF_ARM + (long)Bn*Cn*HWn;      // off_feat bf16 NHWC [8][4096][128]
constexpr long OFF_OM   = OFF_OFT + (long)Bn*Cn*HWn;      // om f32 [8][216][4096]
constexpr long OFF_FUPB = OFF_OM  + (long)Bn*CMn*HWn;     // fup bf16 NHWC [8][4096][128]
// total ~ 105.6 MiB

static __device__ __forceinline__ float ldin(const void* p, long i, bool isbf) {
  if (isbf) return __bfloat162float(((const __hip_bfloat16*)p)[i]);
  return ((const float*)p)[i];
}

// f32 -> bf16 bits (RNE, finite inputs)
static __device__ __forceinline__ unsigned short f2b(float f) {
  unsigned u = __builtin_bit_cast(unsigned, f);
  u += 0x7FFFu + ((u >> 16) & 1u);
  return (unsigned short)(u >> 16);
}
static __device__ __forceinline__ unsigned pack2(float v0, float v1) {
  return ((unsigned)f2b(v1) << 16) | (unsigned)f2b(v0);
}
static __device__ __forceinline__ float b2f(unsigned short s) {
  return __builtin_bit_cast(float, ((unsigned)s) << 16);
}

// ---------------- dtype detector ----------------
__global__ __launch_bounds__(256) void k_detect(const unsigned int* __restrict__ p,
                                                int* __restrict__ flag) {
  __shared__ int cnt[256];
  int t = threadIdx.x;
  int c = 0;
  for (int i = 0; i < 4; ++i) {
    unsigned v = p[t * 4 + i];
    unsigned e = (v >> 7) & 0xFFu;
    c += (e >= 118u && e <= 130u) ? 1 : 0;
  }
  cnt[t] = c;
  __syncthreads();
  for (int s = 128; s > 0; s >>= 1) {
    if (t < s) cnt[t] += cnt[t + s];
    __syncthreads();
  }
  if (t == 0) *flag = (cnt[0] > 512) ? 1 : 0;
}

// ---------------- input conversion ----------------
__global__ __launch_bounds__(256) void k_cvt(const void* __restrict__ src,
                                             float* __restrict__ dst, int n,
                                             const int* __restrict__ flag) {
  int stride = gridDim.x * blockDim.x;
  int i0 = blockIdx.x * blockDim.x + threadIdx.x;
  if (*flag) {
    const __hip_bfloat16* s = (const __hip_bfloat16*)src;
    for (int i = i0; i < n; i += stride) dst[i] = __bfloat162float(s[i]);
  } else {
    const float* s = (const float*)src;
    for (int i = i0; i < n; i += stride) dst[i] = s[i];
  }
}

// w_off [o 128][c 256] -> [c 256][o 128], with 2.0x folded for c>=128
__global__ __launch_bounds__(256) void k_woffT(const void* __restrict__ src,
                                               float* __restrict__ dst,
                                               const int* __restrict__ flag) {
  int i = blockIdx.x * 256 + threadIdx.x;
  if (i >= 2 * Cn * Cn) return;
  int c = i >> 7, o = i & 127;
  bool isbf = (*flag != 0);
  float v = ldin(src, (long)o * 256 + c, isbf);
  if (c >= Cn) v *= 2.0f;
  dst[i] = v;
}

// w_cm [oc 216][c 128][k 9] -> bf16 [tap 9][oc 224 (zero-pad)][c 128]
__global__ __launch_bounds__(256) void k_wcmB(const void* __restrict__ src,
                                              unsigned short* __restrict__ dst,
                                              const int* __restrict__ flag) {
  int i = blockIdx.x * 256 + threadIdx.x;
  if (i >= Kn * 224 * Cn) return;
  int tap = i / (224 * Cn);
  int oc = (i >> 7) % 224;
  int c = i & 127;
  bool isbf = (*flag != 0);
  float v = 0.f;
  if (oc < CMn) v = ldin(src, ((long)oc * Cn + c) * Kn + tap, isbf);
  dst[i] = f2b(v);
}

// w_dcn [o 128][c 128][k 9] -> bf16 [k][o][c]
__global__ __launch_bounds__(256) void k_wdcnB(const void* __restrict__ src,
                                               unsigned short* __restrict__ dst,
                                               const int* __restrict__ flag) {
  int i = blockIdx.x * 256 + threadIdx.x;
  if (i >= Kn * Cn * Cn) return;
  int k = i / (Cn * Cn);
  int o = (i >> 7) & 127;
  int c = i & 127;
  bool isbf = (*flag != 0);
  float v = ldin(src, ((long)o * Cn + c) * Kn + k, isbf);
  dst[i] = f2b(v);
}

// ---------------- gap ----------------
__global__ __launch_bounds__(256) void k_gap(const float* __restrict__ fl,
                                             float* __restrict__ gap) {
  __shared__ float red[256];
  int bc = blockIdx.x, t = threadIdx.x;
  const float* p = fl + (long)bc * HWn;
  float s = 0.f;
  for (int i = t; i < HWn; i += 256) s += p[i];
  red[t] = s;
  __syncthreads();
  for (int k = 128; k > 0; k >>= 1) {
    if (t < k) red[t] += red[t + k];
    __syncthreads();
  }
  if (t == 0) gap[bc] = red[0] * (1.0f / HWn);
}

// ---------------- atten ----------------
__global__ __launch_bounds__(256) void k_atten(const float* __restrict__ gap,
                                               const void* __restrict__ wat,
                                               float* __restrict__ at1p,
                                               const int* __restrict__ flag) {
  int tid = blockIdx.x * 256 + threadIdx.x;
  if (tid >= Bn * Cn) return;
  int b = tid >> 7, o = tid & 127;
  bool isbf = (*flag != 0);
  const float* g = gap + b * Cn;
  float s = 0.f;
  for (int c = 0; c < Cn; ++c) s += g[c] * ldin(wat, (long)o * Cn + c, isbf);
  at1p[tid] = 1.0f + 1.0f / (1.0f + expf(-s));
}

// w1t[b][c][o] = w_fsm[o][c] * (1 + atten[b][c])
__global__ __launch_bounds__(256) void k_w1t(const void* __restrict__ wfsm,
                                             const float* __restrict__ at1p,
                                             float* __restrict__ dst,
                                             const int* __restrict__ flag) {
  int i = blockIdx.x * 256 + threadIdx.x;
  if (i >= Bn * Cn * Cn) return;
  int b = i >> 14, c = (i >> 7) & 127, o = i & 127;
  bool isbf = (*flag != 0);
  dst[i] = ldin(wfsm, (long)o * Cn + c, isbf) * at1p[b * Cn + c];
}

// ---------------- bilinear 2x upsample (f32 NCHW) ----------------
__global__ __launch_bounds__(256) void k_up(const float* __restrict__ fs,
                                            float* __restrict__ fup) {
  int idx = blockIdx.x * 256 + threadIdx.x;
  if (idx >= Bn * Cn * HWn) return;
  int w = idx & 63, h = (idx >> 6) & 63, bc = idx >> 12;
  const float* s = fs + (long)bc * HWs;
  int iy0; float fy;
  if (h & 1) { iy0 = (h - 1) >> 1; fy = 0.25f; } else { iy0 = (h >> 1) - 1; fy = 0.75f; }
  int ix0; float fx;
  if (w & 1) { ix0 = (w - 1) >> 1; fx = 0.25f; } else { ix0 = (w >> 1) - 1; fx = 0.75f; }
  int iy1 = min(iy0 + 1, Hs - 1); iy0 = max(iy0, 0);
  int ix1 = min(ix0 + 1, Ws - 1); ix0 = max(ix0, 0);
  float v = (1.f - fy) * ((1.f - fx) * s[iy0 * Ws + ix0] + fx * s[iy0 * Ws + ix1]) +
            fy        * ((1.f - fx) * s[iy1 * Ws + ix0] + fx * s[iy1 * Ws + ix1]);
  fup[idx] = v;
}

// ---------------- fup f32 NCHW -> bf16 NHWC transpose ----------------
__global__ __launch_bounds__(256) void k_upb(const float* __restrict__ fup,
                                             unsigned short* __restrict__ fupb) {
  __shared__ float xs[128][65];
  const int b = blockIdx.y, p0 = blockIdx.x * 64, t = threadIdx.x;
  const float* src = fup + (long)b * Cn * HWn + p0;
  for (int i = t; i < 128 * 64; i += 256) {
    int c = i >> 6, p = i & 63;
    xs[c][p] = src[(long)c * HWn + p];
  }
  __syncthreads();
  for (int i = t; i < 1024; i += 256) {
    int p = i >> 4, ch = (i & 15) * 8;
    uint4 pk;
    pk.x = pack2(xs[ch + 0][p], xs[ch + 1][p]);
    pk.y = pack2(xs[ch + 2][p], xs[ch + 3][p]);
    pk.z = pack2(xs[ch + 4][p], xs[ch + 5][p]);
    pk.w = pack2(xs[ch + 6][p], xs[ch + 7][p]);
    *(uint4*)(fupb + (((long)(b * HWn + p0 + p)) << 7) + ch) = pk;
  }
}

// ---------------- feat_arm ----------------
__global__ __launch_bounds__(256) void k_farm(const float* __restrict__ fl,
                                              const float* __restrict__ w1t,
                                              float* __restrict__ farm) {
  const int t = threadIdx.x;
  const int b = blockIdx.z, og = blockIdx.y;
  const int pos = blockIdx.x * 256 + t;
  const float* x = fl + (long)b * Cn * HWn + pos;
  const float* wb = w1t + (long)b * Cn * Cn + og * 8;
  float acc[8];
#pragma unroll
  for (int o = 0; o < 8; ++o) acc[o] = 0.f;
  for (int c = 0; c < Cn; ++c) {
    float xv = x[(long)c * HWn];
    const float4* w4 = (const float4*)(wb + (long)c * Cn);
    float4 wa = w4[0], wc = w4[1];
    acc[0] += xv * wa.x; acc[1] += xv * wa.y; acc[2] += xv * wa.z; acc[3] += xv * wa.w;
    acc[4] += xv * wc.x; acc[5] += xv * wc.y; acc[6] += xv * wc.z; acc[7] += xv * wc.w;
  }
#pragma unroll
  for (int o = 0; o < 8; ++o)
    farm[(long)(b * Cn + og * 8 + o) * HWn + pos] = acc[o];
}

// ---------------- off_feat -> bf16 NHWC [b][pos][c] ----------------
__global__ __launch_bounds__(256) void k_offf(const float* __restrict__ arm,
                                              const float* __restrict__ fup,
                                              const float* __restrict__ wot,
                                              unsigned short* __restrict__ oftb) {
  const int t = threadIdx.x;
  const int b = blockIdx.z, og = blockIdx.y;
  const int pos = blockIdx.x * 256 + t;
  const float* xa = arm + (long)b * Cn * HWn + pos;
  const float* xu = fup + (long)b * Cn * HWn + pos;
  const float* wg = wot + og * 8;
  float acc[8];
#pragma unroll
  for (int o = 0; o < 8; ++o) acc[o] = 0.f;
  for (int c = 0; c < Cn; ++c) {
    float xv = xa[(long)c * HWn];
    const float4* w4 = (const float4*)(wg + (long)c * Cn);
    float4 wa = w4[0], wc = w4[1];
    acc[0] += xv * wa.x; acc[1] += xv * wa.y; acc[2] += xv * wa.z; acc[3] += xv * wa.w;
    acc[4] += xv * wc.x; acc[5] += xv * wc.y; acc[6] += xv * wc.z; acc[7] += xv * wc.w;
  }
  for (int c = 0; c < Cn; ++c) {
    float xv = xu[(long)c * HWn];
    const float4* w4 = (const float4*)(wg + (long)(Cn + c) * Cn);
    float4 wa = w4[0], wc = w4[1];
    acc[0] += xv * wa.x; acc[1] += xv * wa.y; acc[2] += xv * wa.z; acc[3] += xv * wa.w;
    acc[4] += xv * wc.x; acc[5] += xv * wc.y; acc[6] += xv * wc.z; acc[7] += xv * wc.w;
  }
  uint4 pk;
  pk.x = pack2(acc[0], acc[1]); pk.y = pack2(acc[2], acc[3]);
  pk.z = pack2(acc[4], acc[5]); pk.w = pack2(acc[6], acc[7]);
  *(uint4*)(oftb + (((long)b * HWn + pos) << 7) + og * 8) = pk;
}

// ---------------- 3x3 conv via bf16 MFMA -> om ----------------
__global__ __launch_bounds__(256) void k_convcm(const unsigned short* __restrict__ xb,
                                                const unsigned short* __restrict__ wb,
                                                const float* __restrict__ bcm,
                                                float* __restrict__ om) {
  __shared__ unsigned int lds[12672];   // 3*66 rows x 256B
  const int h = blockIdx.x, b = blockIdx.y;
  const int t = threadIdx.x, lane = t & 63, wid = t >> 6;
  const int m0 = wid * 16, lm = lane & 15, lh = lane >> 4;

  for (int i = t; i < 3168; i += 256) {
    int pair = i >> 4, chunk = i & 15;
    int row = pair / 66, col = pair % 66;
    int gy = h + row - 1, gx = col - 1;
    uint4 v = {0u, 0u, 0u, 0u};
    if (gy >= 0 && gy < Hn && gx >= 0 && gx < Wn)
      v = *(const uint4*)(xb + (((long)b * HWn + gy * Wn + gx) << 7) + chunk * 8);
    int byte = (pair << 8) + ((chunk << 4) ^ ((col & 7) << 4));
    *(uint4*)((char*)lds + byte) = v;
  }
  __syncthreads();

  f32x4 acc[14];
#pragma unroll
  for (int nt = 0; nt < 14; ++nt) acc[nt] = (f32x4){0.f, 0.f, 0.f, 0.f};

#pragma unroll
  for (int tap = 0; tap < 9; ++tap) {
    const int ky = tap / 3, kx = tap % 3;
    const unsigned short* wt = wb + (long)tap * 224 * Cn + lm * Cn;
    const int colA = m0 + lm + kx;
    const int rowbase = (ky * 66 + colA) << 8;
#pragma unroll
    for (int ks = 0; ks < 4; ++ks) {
      int c0 = ks * 32 + lh * 8;
      bf16x8 af = *(const bf16x8*)((const char*)lds +
                    (rowbase + ((c0 << 1) ^ ((colA & 7) << 4))));
#pragma unroll
      for (int nt = 0; nt < 14; ++nt) {
        bf16x8 bfv = *(const bf16x8*)(wt + (long)nt * 16 * Cn + c0);
        acc[nt] = __builtin_amdgcn_mfma_f32_16x16x32_bf16(af, bfv, acc[nt], 0, 0, 0);
      }
    }
  }

#pragma unroll
  for (int nt = 0; nt < 14; ++nt) {
    int ch = nt * 16 + lm;
    if (ch >= CMn) continue;
    float bias = bcm[ch];
#pragma unroll
    for (int r = 0; r < 4; ++r) {
      int w = m0 + lh * 4 + r;
      float v = acc[nt][r] + bias;
      if (ch >= 144) v = 1.0f / (1.0f + expf(-v));
      om[(((long)(b * CMn + ch)) << 12) + h * Wn + w] = v;
    }
  }
}

// ---------------- fused DCN v2 via bf16 MFMA, NHWC bf16 gather ----------------
// LDS val: 32 rows (w) x 272B (128 ch bf16, padded 256->272 for bank spread).
__global__ __launch_bounds__(256) void k_dcn(const float* __restrict__ om,
                                             const unsigned short* __restrict__ fupb,
                                             const unsigned short* __restrict__ wdb,
                                             const float* __restrict__ bdc,
                                             const float* __restrict__ farm,
                                             void* __restrict__ out,
                                             const int* __restrict__ flagp) {
  __shared__ char valb[32 * 272];
  const int h = blockIdx.x, b = blockIdx.y, w0 = blockIdx.z * 32;
  const int t = threadIdx.x;
  const int lane = t & 63, wid = t >> 6;
  const int gw = t & 31, g = t >> 5;
  f32x4 acc[2][2];
#pragma unroll
  for (int mt = 0; mt < 2; ++mt)
#pragma unroll
    for (int nt = 0; nt < 2; ++nt) acc[mt][nt] = (f32x4){0.f, 0.f, 0.f, 0.f};

  const float* omb = om + (long)b * CMn * HWn + h * Wn;
  const unsigned short* fb = fupb + ((long)b * HWn << 7) + g * 16;
  const int wcol = w0 + gw;

  union U4 { uint4 q; unsigned short s[8]; };

  for (int k = 0; k < Kn; ++k) {
    // ---- phase A: bilinear weights for (g, wcol) ----
    int ch = g * Kn + k;
    float oy = omb[(long)ch * HWn + wcol];
    float ox = omb[(long)(72 + ch) * HWn + wcol];
    float mk = omb[(long)(144 + ch) * HWn + wcol];
    float py = (float)(h + k / 3 - 1) + oy;
    float px = (float)(wcol + k % 3 - 1) + ox;
    float fy = floorf(py), fx = floorf(px);
    float ly = py - fy, lx = px - fx;
    int y0 = (int)fy, x0 = (int)fx, y1 = y0 + 1, x1 = x0 + 1;
    float vy0 = (y0 >= 0 && y0 < Hn) ? 1.f : 0.f;
    float vy1 = (y1 >= 0 && y1 < Hn) ? 1.f : 0.f;
    float vx0 = (x0 >= 0 && x0 < Wn) ? 1.f : 0.f;
    float vx1 = (x1 >= 0 && x1 < Wn) ? 1.f : 0.f;
    int cy0 = min(max(y0, 0), Hn - 1), cy1 = min(max(y1, 0), Hn - 1);
    int cx0 = min(max(x0, 0), Wn - 1), cx1 = min(max(x1, 0), Wn - 1);
    float wq0 = (1.f - ly) * (1.f - lx) * vy0 * vx0 * mk;
    float wq1 = (1.f - ly) * lx * vy0 * vx1 * mk;
    float wq2 = ly * (1.f - lx) * vy1 * vx0 * mk;
    float wq3 = ly * lx * vy1 * vx1 * mk;
    // ---- gather: 4 corners x 32B contiguous (16 ch of this group) ----
    const unsigned short* q0 = fb + ((long)(cy0 * Wn + cx0) << 7);
    const unsigned short* q1 = fb + ((long)(cy0 * Wn + cx1) << 7);
    const unsigned short* q2 = fb + ((long)(cy1 * Wn + cx0) << 7);
    const unsigned short* q3 = fb + ((long)(cy1 * Wn + cx1) << 7);
    U4 a0, a1, b0c, b1c, c0c, c1c, d0c, d1c;
    a0.q = *(const uint4*)q0;        a1.q = *(const uint4*)(q0 + 8);
    b0c.q = *(const uint4*)q1;       b1c.q = *(const uint4*)(q1 + 8);
    c0c.q = *(const uint4*)q2;       c1c.q = *(const uint4*)(q2 + 8);
    d0c.q = *(const uint4*)q3;       d1c.q = *(const uint4*)(q3 + 8);
    float v[16];
#pragma unroll
    for (int j = 0; j < 8; ++j)
      v[j] = wq0 * b2f(a0.s[j]) + wq1 * b2f(b0c.s[j]) +
             wq2 * b2f(c0c.s[j]) + wq3 * b2f(d0c.s[j]);
#pragma unroll
    for (int j = 0; j < 8; ++j)
      v[8 + j] = wq0 * b2f(a1.s[j]) + wq1 * b2f(b1c.s[j]) +
                 wq2 * b2f(c1c.s[j]) + wq3 * b2f(d1c.s[j]);
    uint4 pk0, pk1;
    pk0.x = pack2(v[0], v[1]);  pk0.y = pack2(v[2], v[3]);
    pk0.z = pack2(v[4], v[5]);  pk0.w = pack2(v[6], v[7]);
    pk1.x = pack2(v[8], v[9]);  pk1.y = pack2(v[10], v[11]);
    pk1.z = pack2(v[12], v[13]); pk1.w = pack2(v[14], v[15]);
    char* row = valb + gw * 272 + g * 32;
    *(uint4*)row = pk0;
    *(uint4*)(row + 16) = pk1;
    __syncthreads();
    // ---- MFMA: acc += val[w][c] * wdb[k][o][c] ----
    const unsigned short* wkb = wdb + (long)k * Cn * Cn;
#pragma unroll
    for (int ks = 0; ks < 4; ++ks) {
      int c0 = ks * 32 + 8 * (lane >> 4);
      bf16x8 af[2], bfv[2];
#pragma unroll
      for (int mt = 0; mt < 2; ++mt) {
        int lw = mt * 16 + (lane & 15);
        af[mt] = *(const bf16x8*)(valb + lw * 272 + c0 * 2);
      }
#pragma unroll
      for (int nt = 0; nt < 2; ++nt) {
        int o = wid * 32 + nt * 16 + (lane & 15);
        bfv[nt] = *(const bf16x8*)(wkb + (long)o * Cn + c0);
      }
#pragma unroll
      for (int mt = 0; mt < 2; ++mt)
#pragma unroll
        for (int nt = 0; nt < 2; ++nt)
          acc[mt][nt] = __builtin_amdgcn_mfma_f32_16x16x32_bf16(
              af[mt], bfv[nt], acc[mt][nt], 0, 0, 0);
    }
    __syncthreads();
  }

  bool isbf = (*flagp != 0);
#pragma unroll
  for (int nt = 0; nt < 2; ++nt) {
    int o = wid * 32 + nt * 16 + (lane & 15);
    float bias = bdc[o];
#pragma unroll
    for (int mt = 0; mt < 2; ++mt) {
#pragma unroll
      for (int r = 0; r < 4; ++r) {
        int w = w0 + mt * 16 + (lane >> 4) * 4 + r;
        long oi = (long)(b * Cn + o) * HWn + h * Wn + w;
        float v = acc[mt][nt][r] + bias;
        v = fmaxf(v, 0.f) + farm[oi];
        if (isbf) ((__hip_bfloat16*)out)[oi] = __float2bfloat16(v);
        else      ((float*)out)[oi] = v;
      }
    }
  }
}

// ---------------- launcher ----------------
extern "C" void kernel_launch(void* const* d_in, const int* in_sizes, int n_in,
                              void* d_out, int out_size, void* d_ws, size_t ws_size,
                              hipStream_t stream) {
  (void)in_sizes; (void)n_in; (void)out_size; (void)ws_size;
  const void* feat_l  = d_in[0];
  const void* feat_s  = d_in[1];
  const void* w_atten = d_in[2];
  const void* w_fsm   = d_in[3];
  const void* w_off   = d_in[4];
  const void* w_cm    = d_in[5];
  const void* b_cm    = d_in[6];
  const void* w_dcn   = d_in[7];
  const void* b_dcn   = d_in[8];
  float* ws = (float*)d_ws;
  int* flagw = (int*)d_ws;
  const int* flag = (const int*)d_ws;
  unsigned short* wdb = (unsigned short*)(ws + OFF_WDT);
  unsigned short* wcb = (unsigned short*)(ws + OFF_WCT);
  unsigned short* oftb = (unsigned short*)(ws + OFF_OFT);
  unsigned short* fupb = (unsigned short*)(ws + OFF_FUPB);

  k_detect<<<1, 256, 0, stream>>>((const unsigned int*)feat_l, flagw);
  k_cvt<<<2048, 256, 0, stream>>>(feat_l, ws + OFF_FL, Bn * Cn * HWn, flag);
  k_cvt<<<512, 256, 0, stream>>>(feat_s, ws + OFF_FS, Bn * Cn * HWs, flag);
  k_cvt<<<1, 256, 0, stream>>>(b_cm, ws + OFF_BCM, CMn, flag);
  k_cvt<<<1, 256, 0, stream>>>(b_dcn, ws + OFF_BDC, Cn, flag);
  k_woffT<<<(2 * Cn * Cn + 255) / 256, 256, 0, stream>>>(w_off, ws + OFF_WOT, flag);
  k_wcmB<<<(Kn * 224 * Cn + 255) / 256, 256, 0, stream>>>(w_cm, wcb, flag);
  k_wdcnB<<<(Kn * Cn * Cn + 255) / 256, 256, 0, stream>>>(w_dcn, wdb, flag);
  k_gap<<<Bn * Cn, 256, 0, stream>>>(ws + OFF_FL, ws + OFF_GAP);
  k_atten<<<4, 256, 0, stream>>>(ws + OFF_GAP, w_atten, ws + OFF_AT, flag);
  k_w1t<<<(Bn * Cn * Cn + 255) / 256, 256, 0, stream>>>(w_fsm, ws + OFF_AT, ws + OFF_W1T, flag);
  k_up<<<(Bn * Cn * HWn + 255) / 256, 256, 0, stream>>>(ws + OFF_FS, ws + OFF_FUP);
  k_upb<<<dim3(64, 8), 256, 0, stream>>>(ws + OFF_FUP, fupb);
  k_farm<<<dim3(16, 16, 8), 256, 0, stream>>>(ws + OFF_FL, ws + OFF_W1T, ws + OFF_ARM);
  k_offf<<<dim3(16, 16, 8), 256, 0, stream>>>(ws + OFF_ARM, ws + OFF_FUP, ws + OFF_WOT, oftb);
  k_convcm<<<dim3(64, 8), 256, 0, stream>>>(oftb, wcb, ws + OFF_BCM, ws + OFF_OM);
  k_dcn<<<dim3(64, 8, 2), 256, 0, stream>>>(ws + OFF_OM, fupb, wdb,
                                            ws + OFF_BDC, ws + OFF_ARM, d_out, flag);
}

// Round 5
// 253.285 us; speedup vs baseline: 4.2650x; 1.3036x over previous
//
#include <hip/hip_runtime.h>
#include <hip/hip_bf16.h>

// ---------------- problem constants ----------------
constexpr int Bn = 8, Cn = 128, Hn = 64, Wn = 64, HWn = Hn * Wn;
constexpr int DGn = 8, Kn = 9, CMn = 216;          // CM = DG*3*K
constexpr int Hs = 32, Ws = 32, HWs = Hs * Ws;

typedef __attribute__((ext_vector_type(8))) short bf16x8;
typedef __attribute__((ext_vector_type(4))) float f32x4;

// ---------------- workspace layout (float offsets) ----------------
constexpr long OFF_FLAG = 0;                        // int flag at word 0
constexpr long OFF_FL   = 256;                      // feat_l f32   [8][128][4096]
constexpr long OFF_FS   = OFF_FL  + (long)Bn*Cn*HWn;      // feat_s f32 [8][128][1024]
constexpr long OFF_W1T  = OFF_FS  + (long)Bn*Cn*HWs;      // w1t [b][c][o] 8*128*128
constexpr long OFF_WOT  = OFF_W1T + (long)Bn*Cn*Cn;       // w_offT [c 256][o 128] (2x folded)
constexpr long OFF_WCT  = OFF_WOT + (long)2*Cn*Cn;        // w_cm bf16 slices [18][224][128B-swz]
constexpr long OFF_WDT  = OFF_WCT + (long)Cn*Kn*224;      // w_dcn bf16 [k][o][c]
constexpr long OFF_BCM  = OFF_WDT + (long)Kn*Cn*Cn;       // b_cm (216, padded 256)
constexpr long OFF_BDC  = OFF_BCM + 256;                  // b_dcn (128, padded 256)
constexpr long OFF_GAP  = OFF_BDC + 256;                  // gap [b][c]
constexpr long OFF_AT   = OFF_GAP + (long)Bn*Cn;          // 1+sigmoid(atten) [b][c]
constexpr long OFF_FUP  = OFF_AT  + (long)Bn*Cn;          // feat_up f32 [8][128][4096]
constexpr long OFF_ARM  = OFF_FUP + (long)Bn*Cn*HWn;      // feat_arm f32
constexpr long OFF_OFT  = OFF_ARM + (long)Bn*Cn*HWn;      // off_feat bf16 NHWC [8][4096][128]
constexpr long OFF_OM   = OFF_OFT + (long)Bn*Cn*HWn;      // om f32 [8][216][4096]
constexpr long OFF_FUPB = OFF_OM  + (long)Bn*CMn*HWn;     // fup bf16 NHWC [8][4096][128]

static __device__ __forceinline__ float ldin(const void* p, long i, bool isbf) {
  if (isbf) return __bfloat162float(((const __hip_bfloat16*)p)[i]);
  return ((const float*)p)[i];
}

// f32 -> bf16 bits (RNE, finite inputs)
static __device__ __forceinline__ unsigned short f2b(float f) {
  unsigned u = __builtin_bit_cast(unsigned, f);
  u += 0x7FFFu + ((u >> 16) & 1u);
  return (unsigned short)(u >> 16);
}
static __device__ __forceinline__ unsigned pack2(float v0, float v1) {
  return ((unsigned)f2b(v1) << 16) | (unsigned)f2b(v0);
}
static __device__ __forceinline__ float b2f(unsigned short s) {
  return __builtin_bit_cast(float, ((unsigned)s) << 16);
}

#define GLOAD_LDS16(g, l) __builtin_amdgcn_global_load_lds( \
    (const __attribute__((address_space(1))) void*)(g),     \
    (__attribute__((address_space(3))) void*)(l), 16, 0, 0)

// ---------------- dtype detector ----------------
__global__ __launch_bounds__(256) void k_detect(const unsigned int* __restrict__ p,
                                                int* __restrict__ flag) {
  __shared__ int cnt[256];
  int t = threadIdx.x;
  int c = 0;
  for (int i = 0; i < 4; ++i) {
    unsigned v = p[t * 4 + i];
    unsigned e = (v >> 7) & 0xFFu;
    c += (e >= 118u && e <= 130u) ? 1 : 0;
  }
  cnt[t] = c;
  __syncthreads();
  for (int s = 128; s > 0; s >>= 1) {
    if (t < s) cnt[t] += cnt[t + s];
    __syncthreads();
  }
  if (t == 0) *flag = (cnt[0] > 512) ? 1 : 0;
}

// ---------------- input conversion ----------------
__global__ __launch_bounds__(256) void k_cvt(const void* __restrict__ src,
                                             float* __restrict__ dst, int n,
                                             const int* __restrict__ flag) {
  int stride = gridDim.x * blockDim.x;
  int i0 = blockIdx.x * blockDim.x + threadIdx.x;
  if (*flag) {
    const __hip_bfloat16* s = (const __hip_bfloat16*)src;
    for (int i = i0; i < n; i += stride) dst[i] = __bfloat162float(s[i]);
  } else {
    const float* s = (const float*)src;
    for (int i = i0; i < n; i += stride) dst[i] = s[i];
  }
}

// w_off [o 128][c 256] -> [c 256][o 128], with 2.0x folded for c>=128
__global__ __launch_bounds__(256) void k_woffT(const void* __restrict__ src,
                                               float* __restrict__ dst,
                                               const int* __restrict__ flag) {
  int i = blockIdx.x * 256 + threadIdx.x;
  if (i >= 2 * Cn * Cn) return;
  int c = i >> 7, o = i & 127;
  bool isbf = (*flag != 0);
  float v = ldin(src, (long)o * 256 + c, isbf);
  if (c >= Cn) v *= 2.0f;
  dst[i] = v;
}

// w_cm [oc 216][c 128][k 9] -> bf16 slices [s 18][oc 224][chunk-swizzled 128B]
// s = tap*2 + c_half; within a 128B row, 16B chunk index is XOR'd with (oc&7)
// so the LINEAR global_load_lds image is bank-conflict-free for the reader.
__global__ __launch_bounds__(256) void k_wcmB(const void* __restrict__ src,
                                              unsigned short* __restrict__ dst,
                                              const int* __restrict__ flag) {
  int i = blockIdx.x * 256 + threadIdx.x;
  if (i >= 18 * 224 * 64) return;
  int s = i / (224 * 64);
  int rem = i % (224 * 64);
  int oc = rem >> 6;
  int c_off = rem & 63;
  int tap = s >> 1, ck = s & 1;
  int c = ck * 64 + c_off;
  bool isbf = (*flag != 0);
  float v = 0.f;
  if (oc < CMn) v = ldin(src, ((long)oc * Cn + c) * Kn + tap, isbf);
  int chunk = c_off >> 3, e = c_off & 7;
  int pc = chunk ^ (oc & 7);
  dst[(long)s * 14336 + oc * 64 + pc * 8 + e] = f2b(v);
}

// w_dcn [o 128][c 128][k 9] -> bf16 [k][o][c]
__global__ __launch_bounds__(256) void k_wdcnB(const void* __restrict__ src,
                                               unsigned short* __restrict__ dst,
                                               const int* __restrict__ flag) {
  int i = blockIdx.x * 256 + threadIdx.x;
  if (i >= Kn * Cn * Cn) return;
  int k = i / (Cn * Cn);
  int o = (i >> 7) & 127;
  int c = i & 127;
  bool isbf = (*flag != 0);
  float v = ldin(src, ((long)o * Cn + c) * Kn + k, isbf);
  dst[i] = f2b(v);
}

// ---------------- gap ----------------
__global__ __launch_bounds__(256) void k_gap(const float* __restrict__ fl,
                                             float* __restrict__ gap) {
  __shared__ float red[256];
  int bc = blockIdx.x, t = threadIdx.x;
  const float* p = fl + (long)bc * HWn;
  float s = 0.f;
  for (int i = t; i < HWn; i += 256) s += p[i];
  red[t] = s;
  __syncthreads();
  for (int k = 128; k > 0; k >>= 1) {
    if (t < k) red[t] += red[t + k];
    __syncthreads();
  }
  if (t == 0) gap[bc] = red[0] * (1.0f / HWn);
}

// ---------------- atten ----------------
__global__ __launch_bounds__(256) void k_atten(const float* __restrict__ gap,
                                               const void* __restrict__ wat,
                                               float* __restrict__ at1p,
                                               const int* __restrict__ flag) {
  int tid = blockIdx.x * 256 + threadIdx.x;
  if (tid >= Bn * Cn) return;
  int b = tid >> 7, o = tid & 127;
  bool isbf = (*flag != 0);
  const float* g = gap + b * Cn;
  float s = 0.f;
  for (int c = 0; c < Cn; ++c) s += g[c] * ldin(wat, (long)o * Cn + c, isbf);
  at1p[tid] = 1.0f + 1.0f / (1.0f + expf(-s));
}

// w1t[b][c][o] = w_fsm[o][c] * (1 + atten[b][c])
__global__ __launch_bounds__(256) void k_w1t(const void* __restrict__ wfsm,
                                             const float* __restrict__ at1p,
                                             float* __restrict__ dst,
                                             const int* __restrict__ flag) {
  int i = blockIdx.x * 256 + threadIdx.x;
  if (i >= Bn * Cn * Cn) return;
  int b = i >> 14, c = (i >> 7) & 127, o = i & 127;
  bool isbf = (*flag != 0);
  dst[i] = ldin(wfsm, (long)o * Cn + c, isbf) * at1p[b * Cn + c];
}

// ---------------- bilinear 2x upsample (f32 NCHW) ----------------
__global__ __launch_bounds__(256) void k_up(const float* __restrict__ fs,
                                            float* __restrict__ fup) {
  int idx = blockIdx.x * 256 + threadIdx.x;
  if (idx >= Bn * Cn * HWn) return;
  int w = idx & 63, h = (idx >> 6) & 63, bc = idx >> 12;
  const float* s = fs + (long)bc * HWs;
  int iy0; float fy;
  if (h & 1) { iy0 = (h - 1) >> 1; fy = 0.25f; } else { iy0 = (h >> 1) - 1; fy = 0.75f; }
  int ix0; float fx;
  if (w & 1) { ix0 = (w - 1) >> 1; fx = 0.25f; } else { ix0 = (w >> 1) - 1; fx = 0.75f; }
  int iy1 = min(iy0 + 1, Hs - 1); iy0 = max(iy0, 0);
  int ix1 = min(ix0 + 1, Ws - 1); ix0 = max(ix0, 0);
  float v = (1.f - fy) * ((1.f - fx) * s[iy0 * Ws + ix0] + fx * s[iy0 * Ws + ix1]) +
            fy        * ((1.f - fx) * s[iy1 * Ws + ix0] + fx * s[iy1 * Ws + ix1]);
  fup[idx] = v;
}

// ---------------- fup f32 NCHW -> bf16 NHWC transpose ----------------
__global__ __launch_bounds__(256) void k_upb(const float* __restrict__ fup,
                                             unsigned short* __restrict__ fupb) {
  __shared__ float xs[128][65];
  const int b = blockIdx.y, p0 = blockIdx.x * 64, t = threadIdx.x;
  const float* src = fup + (long)b * Cn * HWn + p0;
  for (int i = t; i < 128 * 64; i += 256) {
    int c = i >> 6, p = i & 63;
    xs[c][p] = src[(long)c * HWn + p];
  }
  __syncthreads();
  for (int i = t; i < 1024; i += 256) {
    int p = i >> 4, ch = (i & 15) * 8;
    uint4 pk;
    pk.x = pack2(xs[ch + 0][p], xs[ch + 1][p]);
    pk.y = pack2(xs[ch + 2][p], xs[ch + 3][p]);
    pk.z = pack2(xs[ch + 4][p], xs[ch + 5][p]);
    pk.w = pack2(xs[ch + 6][p], xs[ch + 7][p]);
    *(uint4*)(fupb + (((long)(b * HWn + p0 + p)) << 7) + ch) = pk;
  }
}

// ---------------- feat_arm ----------------
__global__ __launch_bounds__(256) void k_farm(const float* __restrict__ fl,
                                              const float* __restrict__ w1t,
                                              float* __restrict__ farm) {
  const int t = threadIdx.x;
  const int b = blockIdx.z, og = blockIdx.y;
  const int pos = blockIdx.x * 256 + t;
  const float* x = fl + (long)b * Cn * HWn + pos;
  const float* wb = w1t + (long)b * Cn * Cn + og * 8;
  float acc[8];
#pragma unroll
  for (int o = 0; o < 8; ++o) acc[o] = 0.f;
  for (int c = 0; c < Cn; ++c) {
    float xv = x[(long)c * HWn];
    const float4* w4 = (const float4*)(wb + (long)c * Cn);
    float4 wa = w4[0], wc = w4[1];
    acc[0] += xv * wa.x; acc[1] += xv * wa.y; acc[2] += xv * wa.z; acc[3] += xv * wa.w;
    acc[4] += xv * wc.x; acc[5] += xv * wc.y; acc[6] += xv * wc.z; acc[7] += xv * wc.w;
  }
#pragma unroll
  for (int o = 0; o < 8; ++o)
    farm[(long)(b * Cn + og * 8 + o) * HWn + pos] = acc[o];
}

// ---------------- off_feat -> bf16 NHWC [b][pos][c] ----------------
__global__ __launch_bounds__(256) void k_offf(const float* __restrict__ arm,
                                              const float* __restrict__ fup,
                                              const float* __restrict__ wot,
                                              unsigned short* __restrict__ oftb) {
  const int t = threadIdx.x;
  const int b = blockIdx.z, og = blockIdx.y;
  const int pos = blockIdx.x * 256 + t;
  const float* xa = arm + (long)b * Cn * HWn + pos;
  const float* xu = fup + (long)b * Cn * HWn + pos;
  const float* wg = wot + og * 8;
  float acc[8];
#pragma unroll
  for (int o = 0; o < 8; ++o) acc[o] = 0.f;
  for (int c = 0; c < Cn; ++c) {
    float xv = xa[(long)c * HWn];
    const float4* w4 = (const float4*)(wg + (long)c * Cn);
    float4 wa = w4[0], wc = w4[1];
    acc[0] += xv * wa.x; acc[1] += xv * wa.y; acc[2] += xv * wa.z; acc[3] += xv * wa.w;
    acc[4] += xv * wc.x; acc[5] += xv * wc.y; acc[6] += xv * wc.z; acc[7] += xv * wc.w;
  }
  for (int c = 0; c < Cn; ++c) {
    float xv = xu[(long)c * HWn];
    const float4* w4 = (const float4*)(wg + (long)(Cn + c) * Cn);
    float4 wa = w4[0], wc = w4[1];
    acc[0] += xv * wa.x; acc[1] += xv * wa.y; acc[2] += xv * wa.z; acc[3] += xv * wa.w;
    acc[4] += xv * wc.x; acc[5] += xv * wc.y; acc[6] += xv * wc.z; acc[7] += xv * wc.w;
  }
  uint4 pk;
  pk.x = pack2(acc[0], acc[1]); pk.y = pack2(acc[2], acc[3]);
  pk.z = pack2(acc[4], acc[5]); pk.w = pack2(acc[6], acc[7]);
  *(uint4*)(oftb + (((long)b * HWn + pos) << 7) + og * 8) = pk;
}

// ---------------- 3x3 conv via bf16 MFMA, LDS-staged weights -> om ----------------
// Block = (h, b): M=64 (w), N=224 (oc), K=1152 (9 taps x 128 c).
// 18 slices of (tap, c-half): weights 28,672 B each, double-buffered in LDS via
// global_load_lds (linear image pre-swizzled by k_wcmB). A-frags read straight
// from global NHWC oftb (L1/L2-resident, halo-reused).
// 4 waves: wave = (mi = wid&1 -> M 32, ni = wid>>1 -> N 112).
__global__ __launch_bounds__(256) void k_convcm(const unsigned short* __restrict__ xb,
                                                const unsigned short* __restrict__ wsl,
                                                const float* __restrict__ bcm,
                                                float* __restrict__ om) {
  __shared__ unsigned short wlds[2][14336];   // 2 x 28,672 B
  const int h = blockIdx.x, b = blockIdx.y;
  const int t = threadIdx.x, lane = t & 63, wv = t >> 6;
  const int mi = wv & 1, ni = wv >> 1;
  const int lm = lane & 15, lh = lane >> 4;

  f32x4 acc[2][7];
#pragma unroll
  for (int mt = 0; mt < 2; ++mt)
#pragma unroll
    for (int nt = 0; nt < 7; ++nt) acc[mt][nt] = (f32x4){0.f, 0.f, 0.f, 0.f};

  auto stage = [&](int s, int bufi) {
    const char* src = (const char*)(wsl + (long)s * 14336);
    char* dstb = (char*)&wlds[bufi][0];
#pragma unroll
    for (int i2 = 0; i2 < 7; ++i2) {
      int off = (wv * 7 + i2) * 1024;
      GLOAD_LDS16(src + off + lane * 16, dstb + off);
    }
  };

  stage(0, 0);
  __syncthreads();

  for (int s = 0; s < 18; ++s) {
    const int cur = s & 1;
    if (s < 17) stage(s + 1, cur ^ 1);
    const int tap = s >> 1, ck = s & 1;
    const int ky = tap / 3, kx = tap % 3;
    const int gy = h + ky - 1;
    const bool gyok = ((unsigned)gy < (unsigned)Hn);
    const int gyc = min(max(gy, 0), Hn - 1);

    // A-frags from global NHWC
    bf16x8 af[2][2];
#pragma unroll
    for (int mt = 0; mt < 2; ++mt) {
      int wpos = mi * 32 + mt * 16 + lm;
      int gx = wpos + kx - 1;
      bool ok = gyok && ((unsigned)gx < (unsigned)Wn);
      int gxc = min(max(gx, 0), Wn - 1);
      const unsigned short* ap = xb + (((long)(b * HWn + gyc * Wn + gxc)) << 7)
                                    + ck * 64 + lh * 8;
#pragma unroll
      for (int ksub = 0; ksub < 2; ++ksub) {
        bf16x8 v = *(const bf16x8*)(ap + ksub * 32);
        af[mt][ksub] = ok ? v : (bf16x8)(short)0;
      }
    }

    // B from LDS (swizzled) + MFMA
    const char* wbase = (const char*)&wlds[cur][0];
#pragma unroll
    for (int ksub = 0; ksub < 2; ++ksub) {
      int jj = ksub * 4 + lh;
#pragma unroll
      for (int nt = 0; nt < 7; ++nt) {
        int oc = ni * 112 + nt * 16 + lm;
        bf16x8 bfv = *(const bf16x8*)(wbase + oc * 128 + ((jj ^ (oc & 7)) << 4));
#pragma unroll
        for (int mt = 0; mt < 2; ++mt)
          acc[mt][nt] = __builtin_amdgcn_mfma_f32_16x16x32_bf16(
              af[mt][ksub], bfv, acc[mt][nt], 0, 0, 0);
      }
    }
    __syncthreads();
  }

#pragma unroll
  for (int nt = 0; nt < 7; ++nt) {
    int ch = ni * 112 + nt * 16 + lm;
    if (ch >= CMn) continue;
    float bias = bcm[ch];
#pragma unroll
    for (int mt = 0; mt < 2; ++mt) {
#pragma unroll
      for (int r = 0; r < 4; ++r) {
        int w = mi * 32 + mt * 16 + lh * 4 + r;
        float v = acc[mt][nt][r] + bias;
        if (ch >= 144) v = 1.0f / (1.0f + expf(-v));
        om[(((long)(b * CMn + ch)) << 12) + h * Wn + w] = v;
      }
    }
  }
}

// ---------------- fused DCN v2 via bf16 MFMA, NHWC bf16 gather ----------------
__global__ __launch_bounds__(256) void k_dcn(const float* __restrict__ om,
                                             const unsigned short* __restrict__ fupb,
                                             const unsigned short* __restrict__ wdb,
                                             const float* __restrict__ bdc,
                                             const float* __restrict__ farm,
                                             void* __restrict__ out,
                                             const int* __restrict__ flagp) {
  __shared__ char valb[32 * 272];
  const int h = blockIdx.x, b = blockIdx.y, w0 = blockIdx.z * 32;
  const int t = threadIdx.x;
  const int lane = t & 63, wid = t >> 6;
  const int gw = t & 31, g = t >> 5;
  f32x4 acc[2][2];
#pragma unroll
  for (int mt = 0; mt < 2; ++mt)
#pragma unroll
    for (int nt = 0; nt < 2; ++nt) acc[mt][nt] = (f32x4){0.f, 0.f, 0.f, 0.f};

  const float* omb = om + (long)b * CMn * HWn + h * Wn;
  const unsigned short* fb = fupb + ((long)b * HWn << 7) + g * 16;
  const int wcol = w0 + gw;

  union U4 { uint4 q; unsigned short s[8]; };

  for (int k = 0; k < Kn; ++k) {
    int ch = g * Kn + k;
    float oy = omb[(long)ch * HWn + wcol];
    float ox = omb[(long)(72 + ch) * HWn + wcol];
    float mk = omb[(long)(144 + ch) * HWn + wcol];
    float py = (float)(h + k / 3 - 1) + oy;
    float px = (float)(wcol + k % 3 - 1) + ox;
    float fy = floorf(py), fx = floorf(px);
    float ly = py - fy, lx = px - fx;
    int y0 = (int)fy, x0 = (int)fx, y1 = y0 + 1, x1 = x0 + 1;
    float vy0 = (y0 >= 0 && y0 < Hn) ? 1.f : 0.f;
    float vy1 = (y1 >= 0 && y1 < Hn) ? 1.f : 0.f;
    float vx0 = (x0 >= 0 && x0 < Wn) ? 1.f : 0.f;
    float vx1 = (x1 >= 0 && x1 < Wn) ? 1.f : 0.f;
    int cy0 = min(max(y0, 0), Hn - 1), cy1 = min(max(y1, 0), Hn - 1);
    int cx0 = min(max(x0, 0), Wn - 1), cx1 = min(max(x1, 0), Wn - 1);
    float wq0 = (1.f - ly) * (1.f - lx) * vy0 * vx0 * mk;
    float wq1 = (1.f - ly) * lx * vy0 * vx1 * mk;
    float wq2 = ly * (1.f - lx) * vy1 * vx0 * mk;
    float wq3 = ly * lx * vy1 * vx1 * mk;
    const unsigned short* q0 = fb + ((long)(cy0 * Wn + cx0) << 7);
    const unsigned short* q1 = fb + ((long)(cy0 * Wn + cx1) << 7);
    const unsigned short* q2 = fb + ((long)(cy1 * Wn + cx0) << 7);
    const unsigned short* q3 = fb + ((long)(cy1 * Wn + cx1) << 7);
    U4 a0, a1, b0c, b1c, c0c, c1c, d0c, d1c;
    a0.q = *(const uint4*)q0;        a1.q = *(const uint4*)(q0 + 8);
    b0c.q = *(const uint4*)q1;       b1c.q = *(const uint4*)(q1 + 8);
    c0c.q = *(const uint4*)q2;       c1c.q = *(const uint4*)(q2 + 8);
    d0c.q = *(const uint4*)q3;       d1c.q = *(const uint4*)(q3 + 8);
    float v[16];
#pragma unroll
    for (int j = 0; j < 8; ++j)
      v[j] = wq0 * b2f(a0.s[j]) + wq1 * b2f(b0c.s[j]) +
             wq2 * b2f(c0c.s[j]) + wq3 * b2f(d0c.s[j]);
#pragma unroll
    for (int j = 0; j < 8; ++j)
      v[8 + j] = wq0 * b2f(a1.s[j]) + wq1 * b2f(b1c.s[j]) +
                 wq2 * b2f(c1c.s[j]) + wq3 * b2f(d1c.s[j]);
    uint4 pk0, pk1;
    pk0.x = pack2(v[0], v[1]);  pk0.y = pack2(v[2], v[3]);
    pk0.z = pack2(v[4], v[5]);  pk0.w = pack2(v[6], v[7]);
    pk1.x = pack2(v[8], v[9]);  pk1.y = pack2(v[10], v[11]);
    pk1.z = pack2(v[12], v[13]); pk1.w = pack2(v[14], v[15]);
    char* row = valb + gw * 272 + g * 32;
    *(uint4*)row = pk0;
    *(uint4*)(row + 16) = pk1;
    __syncthreads();
    const unsigned short* wkb = wdb + (long)k * Cn * Cn;
#pragma unroll
    for (int ks = 0; ks < 4; ++ks) {
      int c0 = ks * 32 + 8 * (lane >> 4);
      bf16x8 af[2], bfv[2];
#pragma unroll
      for (int mt = 0; mt < 2; ++mt) {
        int lw = mt * 16 + (lane & 15);
        af[mt] = *(const bf16x8*)(valb + lw * 272 + c0 * 2);
      }
#pragma unroll
      for (int nt = 0; nt < 2; ++nt) {
        int o = wid * 32 + nt * 16 + (lane & 15);
        bfv[nt] = *(const bf16x8*)(wkb + (long)o * Cn + c0);
      }
#pragma unroll
      for (int mt = 0; mt < 2; ++mt)
#pragma unroll
        for (int nt = 0; nt < 2; ++nt)
          acc[mt][nt] = __builtin_amdgcn_mfma_f32_16x16x32_bf16(
              af[mt], bfv[nt], acc[mt][nt], 0, 0, 0);
    }
    __syncthreads();
  }

  bool isbf = (*flagp != 0);
#pragma unroll
  for (int nt = 0; nt < 2; ++nt) {
    int o = wid * 32 + nt * 16 + (lane & 15);
    float bias = bdc[o];
#pragma unroll
    for (int mt = 0; mt < 2; ++mt) {
#pragma unroll
      for (int r = 0; r < 4; ++r) {
        int w = w0 + mt * 16 + (lane >> 4) * 4 + r;
        long oi = (long)(b * Cn + o) * HWn + h * Wn + w;
        float v = acc[mt][nt][r] + bias;
        v = fmaxf(v, 0.f) + farm[oi];
        if (isbf) ((__hip_bfloat16*)out)[oi] = __float2bfloat16(v);
        else      ((float*)out)[oi] = v;
      }
    }
  }
}

// ---------------- launcher ----------------
extern "C" void kernel_launch(void* const* d_in, const int* in_sizes, int n_in,
                              void* d_out, int out_size, void* d_ws, size_t ws_size,
                              hipStream_t stream) {
  (void)in_sizes; (void)n_in; (void)out_size; (void)ws_size;
  const void* feat_l  = d_in[0];
  const void* feat_s  = d_in[1];
  const void* w_atten = d_in[2];
  const void* w_fsm   = d_in[3];
  const void* w_off   = d_in[4];
  const void* w_cm    = d_in[5];
  const void* b_cm    = d_in[6];
  const void* w_dcn   = d_in[7];
  const void* b_dcn   = d_in[8];
  float* ws = (float*)d_ws;
  int* flagw = (int*)d_ws;
  const int* flag = (const int*)d_ws;
  unsigned short* wdb = (unsigned short*)(ws + OFF_WDT);
  unsigned short* wcb = (unsigned short*)(ws + OFF_WCT);
  unsigned short* oftb = (unsigned short*)(ws + OFF_OFT);
  unsigned short* fupb = (unsigned short*)(ws + OFF_FUPB);

  k_detect<<<1, 256, 0, stream>>>((const unsigned int*)feat_l, flagw);
  k_cvt<<<2048, 256, 0, stream>>>(feat_l, ws + OFF_FL, Bn * Cn * HWn, flag);
  k_cvt<<<512, 256, 0, stream>>>(feat_s, ws + OFF_FS, Bn * Cn * HWs, flag);
  k_cvt<<<1, 256, 0, stream>>>(b_cm, ws + OFF_BCM, CMn, flag);
  k_cvt<<<1, 256, 0, stream>>>(b_dcn, ws + OFF_BDC, Cn, flag);
  k_woffT<<<(2 * Cn * Cn + 255) / 256, 256, 0, stream>>>(w_off, ws + OFF_WOT, flag);
  k_wcmB<<<(18 * 224 * 64 + 255) / 256, 256, 0, stream>>>(w_cm, wcb, flag);
  k_wdcnB<<<(Kn * Cn * Cn + 255) / 256, 256, 0, stream>>>(w_dcn, wdb, flag);
  k_gap<<<Bn * Cn, 256, 0, stream>>>(ws + OFF_FL, ws + OFF_GAP);
  k_atten<<<4, 256, 0, stream>>>(ws + OFF_GAP, w_atten, ws + OFF_AT, flag);
  k_w1t<<<(Bn * Cn * Cn + 255) / 256, 256, 0, stream>>>(w_fsm, ws + OFF_AT, ws + OFF_W1T, flag);
  k_up<<<(Bn * Cn * HWn + 255) / 256, 256, 0, stream>>>(ws + OFF_FS, ws + OFF_FUP);
  k_upb<<<dim3(64, 8), 256, 0, stream>>>(ws + OFF_FUP, fupb);
  k_farm<<<dim3(16, 16, 8), 256, 0, stream>>>(ws + OFF_FL, ws + OFF_W1T, ws + OFF_ARM);
  k_offf<<<dim3(16, 16, 8), 256, 0, stream>>>(ws + OFF_ARM, ws + OFF_FUP, ws + OFF_WOT, oftb);
  k_convcm<<<dim3(64, 8), 256, 0, stream>>>(oftb, wcb, ws + OFF_BCM, ws + OFF_OM);
  k_dcn<<<dim3(64, 8, 2), 256, 0, stream>>>(ws + OFF_OM, fupb, wdb,
                                            ws + OFF_BDC, ws + OFF_ARM, d_out, flag);
}

// Round 6
// 252.808 us; speedup vs baseline: 4.2730x; 1.0019x over previous
//
#include <hip/hip_runtime.h>
#include <hip/hip_bf16.h>

// ---------------- problem constants ----------------
constexpr int Bn = 8, Cn = 128, Hn = 64, Wn = 64, HWn = Hn * Wn;
constexpr int DGn = 8, Kn = 9, CMn = 216;          // CM = DG*3*K
constexpr int Hs = 32, Ws = 32, HWs = Hs * Ws;

typedef __attribute__((ext_vector_type(8))) short bf16x8;
typedef __attribute__((ext_vector_type(4))) float f32x4;

// ---------------- workspace layout (float offsets) ----------------
constexpr long OFF_FLAG = 0;                        // int flag at word 0
constexpr long OFF_FL   = 256;                      // feat_l f32   [8][128][4096]
constexpr long OFF_FS   = OFF_FL  + (long)Bn*Cn*HWn;      // feat_s f32 [8][128][1024]
constexpr long OFF_W1T  = OFF_FS  + (long)Bn*Cn*HWs;      // w1t [b][c][o] 8*128*128
constexpr long OFF_WOT  = OFF_W1T + (long)Bn*Cn*Cn;       // w_offT [c 256][o 128] (2x folded)
constexpr long OFF_WCT  = OFF_WOT + (long)2*Cn*Cn;        // w_cm bf16 slices [18][224][128B-swz]
constexpr long OFF_WDT  = OFF_WCT + (long)Cn*Kn*224;      // w_dcn bf16 [k][o][c]
constexpr long OFF_BCM  = OFF_WDT + (long)Kn*Cn*Cn;       // b_cm (216, padded 256)
constexpr long OFF_BDC  = OFF_BCM + 256;                  // b_dcn (128, padded 256)
constexpr long OFF_GAP  = OFF_BDC + 256;                  // gap [b][c]
constexpr long OFF_AT   = OFF_GAP + (long)Bn*Cn;          // 1+sigmoid(atten) [b][c]
constexpr long OFF_FUP  = OFF_AT  + (long)Bn*Cn;          // feat_up f32 [8][128][4096]
constexpr long OFF_ARM  = OFF_FUP + (long)Bn*Cn*HWn;      // feat_arm f32
constexpr long OFF_OFT  = OFF_ARM + (long)Bn*Cn*HWn;      // off_feat bf16 NHWC [8][4096][128]
constexpr long OFF_OM   = OFF_OFT + (long)Bn*Cn*HWn;      // om f32 [b][h][216][64]
constexpr long OFF_FUPB = OFF_OM  + (long)Bn*CMn*HWn;     // fup bf16 NHWC [8][4096][128]

static __device__ __forceinline__ float ldin(const void* p, long i, bool isbf) {
  if (isbf) return __bfloat162float(((const __hip_bfloat16*)p)[i]);
  return ((const float*)p)[i];
}

// f32 -> bf16 bits (RNE, finite inputs)
static __device__ __forceinline__ unsigned short f2b(float f) {
  unsigned u = __builtin_bit_cast(unsigned, f);
  u += 0x7FFFu + ((u >> 16) & 1u);
  return (unsigned short)(u >> 16);
}
static __device__ __forceinline__ unsigned pack2(float v0, float v1) {
  return ((unsigned)f2b(v1) << 16) | (unsigned)f2b(v0);
}
static __device__ __forceinline__ float b2f(unsigned short s) {
  return __builtin_bit_cast(float, ((unsigned)s) << 16);
}

#define GLOAD_LDS16(g, l) __builtin_amdgcn_global_load_lds( \
    (const __attribute__((address_space(1))) void*)(g),     \
    (__attribute__((address_space(3))) void*)(l), 16, 0, 0)

// ---------------- dtype detector ----------------
__global__ __launch_bounds__(256) void k_detect(const unsigned int* __restrict__ p,
                                                int* __restrict__ flag) {
  __shared__ int cnt[256];
  int t = threadIdx.x;
  int c = 0;
  for (int i = 0; i < 4; ++i) {
    unsigned v = p[t * 4 + i];
    unsigned e = (v >> 7) & 0xFFu;
    c += (e >= 118u && e <= 130u) ? 1 : 0;
  }
  cnt[t] = c;
  __syncthreads();
  for (int s = 128; s > 0; s >>= 1) {
    if (t < s) cnt[t] += cnt[t + s];
    __syncthreads();
  }
  if (t == 0) *flag = (cnt[0] > 512) ? 1 : 0;
}

// ---------------- input conversion ----------------
__global__ __launch_bounds__(256) void k_cvt(const void* __restrict__ src,
                                             float* __restrict__ dst, int n,
                                             const int* __restrict__ flag) {
  int stride = gridDim.x * blockDim.x;
  int i0 = blockIdx.x * blockDim.x + threadIdx.x;
  if (*flag) {
    const __hip_bfloat16* s = (const __hip_bfloat16*)src;
    for (int i = i0; i < n; i += stride) dst[i] = __bfloat162float(s[i]);
  } else {
    const float* s = (const float*)src;
    for (int i = i0; i < n; i += stride) dst[i] = s[i];
  }
}

// w_off [o 128][c 256] -> [c 256][o 128], with 2.0x folded for c>=128
__global__ __launch_bounds__(256) void k_woffT(const void* __restrict__ src,
                                               float* __restrict__ dst,
                                               const int* __restrict__ flag) {
  int i = blockIdx.x * 256 + threadIdx.x;
  if (i >= 2 * Cn * Cn) return;
  int c = i >> 7, o = i & 127;
  bool isbf = (*flag != 0);
  float v = ldin(src, (long)o * 256 + c, isbf);
  if (c >= Cn) v *= 2.0f;
  dst[i] = v;
}

// w_cm [oc 216][c 128][k 9] -> bf16 slices [s 18][oc 224][chunk-swizzled 128B]
__global__ __launch_bounds__(256) void k_wcmB(const void* __restrict__ src,
                                              unsigned short* __restrict__ dst,
                                              const int* __restrict__ flag) {
  int i = blockIdx.x * 256 + threadIdx.x;
  if (i >= 18 * 224 * 64) return;
  int s = i / (224 * 64);
  int rem = i % (224 * 64);
  int oc = rem >> 6;
  int c_off = rem & 63;
  int tap = s >> 1, ck = s & 1;
  int c = ck * 64 + c_off;
  bool isbf = (*flag != 0);
  float v = 0.f;
  if (oc < CMn) v = ldin(src, ((long)oc * Cn + c) * Kn + tap, isbf);
  int chunk = c_off >> 3, e = c_off & 7;
  int pc = chunk ^ (oc & 7);
  dst[(long)s * 14336 + oc * 64 + pc * 8 + e] = f2b(v);
}

// w_dcn [o 128][c 128][k 9] -> bf16 [k][o][c]
__global__ __launch_bounds__(256) void k_wdcnB(const void* __restrict__ src,
                                               unsigned short* __restrict__ dst,
                                               const int* __restrict__ flag) {
  int i = blockIdx.x * 256 + threadIdx.x;
  if (i >= Kn * Cn * Cn) return;
  int k = i / (Cn * Cn);
  int o = (i >> 7) & 127;
  int c = i & 127;
  bool isbf = (*flag != 0);
  float v = ldin(src, ((long)o * Cn + c) * Kn + k, isbf);
  dst[i] = f2b(v);
}

// ---------------- gap ----------------
__global__ __launch_bounds__(256) void k_gap(const float* __restrict__ fl,
                                             float* __restrict__ gap) {
  __shared__ float red[256];
  int bc = blockIdx.x, t = threadIdx.x;
  const float* p = fl + (long)bc * HWn;
  float s = 0.f;
  for (int i = t; i < HWn; i += 256) s += p[i];
  red[t] = s;
  __syncthreads();
  for (int k = 128; k > 0; k >>= 1) {
    if (t < k) red[t] += red[t + k];
    __syncthreads();
  }
  if (t == 0) gap[bc] = red[0] * (1.0f / HWn);
}

// ---------------- atten ----------------
__global__ __launch_bounds__(256) void k_atten(const float* __restrict__ gap,
                                               const void* __restrict__ wat,
                                               float* __restrict__ at1p,
                                               const int* __restrict__ flag) {
  int tid = blockIdx.x * 256 + threadIdx.x;
  if (tid >= Bn * Cn) return;
  int b = tid >> 7, o = tid & 127;
  bool isbf = (*flag != 0);
  const float* g = gap + b * Cn;
  float s = 0.f;
  for (int c = 0; c < Cn; ++c) s += g[c] * ldin(wat, (long)o * Cn + c, isbf);
  at1p[tid] = 1.0f + 1.0f / (1.0f + expf(-s));
}

// w1t[b][c][o] = w_fsm[o][c] * (1 + atten[b][c])
__global__ __launch_bounds__(256) void k_w1t(const void* __restrict__ wfsm,
                                             const float* __restrict__ at1p,
                                             float* __restrict__ dst,
                                             const int* __restrict__ flag) {
  int i = blockIdx.x * 256 + threadIdx.x;
  if (i >= Bn * Cn * Cn) return;
  int b = i >> 14, c = (i >> 7) & 127, o = i & 127;
  bool isbf = (*flag != 0);
  dst[i] = ldin(wfsm, (long)o * Cn + c, isbf) * at1p[b * Cn + c];
}

// ---------------- bilinear 2x upsample (f32 NCHW) ----------------
__global__ __launch_bounds__(256) void k_up(const float* __restrict__ fs,
                                            float* __restrict__ fup) {
  int idx = blockIdx.x * 256 + threadIdx.x;
  if (idx >= Bn * Cn * HWn) return;
  int w = idx & 63, h = (idx >> 6) & 63, bc = idx >> 12;
  const float* s = fs + (long)bc * HWs;
  int iy0; float fy;
  if (h & 1) { iy0 = (h - 1) >> 1; fy = 0.25f; } else { iy0 = (h >> 1) - 1; fy = 0.75f; }
  int ix0; float fx;
  if (w & 1) { ix0 = (w - 1) >> 1; fx = 0.25f; } else { ix0 = (w >> 1) - 1; fx = 0.75f; }
  int iy1 = min(iy0 + 1, Hs - 1); iy0 = max(iy0, 0);
  int ix1 = min(ix0 + 1, Ws - 1); ix0 = max(ix0, 0);
  float v = (1.f - fy) * ((1.f - fx) * s[iy0 * Ws + ix0] + fx * s[iy0 * Ws + ix1]) +
            fy        * ((1.f - fx) * s[iy1 * Ws + ix0] + fx * s[iy1 * Ws + ix1]);
  fup[idx] = v;
}

// ---------------- fup f32 NCHW -> bf16 NHWC transpose ----------------
__global__ __launch_bounds__(256) void k_upb(const float* __restrict__ fup,
                                             unsigned short* __restrict__ fupb) {
  __shared__ float xs[128][65];
  const int b = blockIdx.y, p0 = blockIdx.x * 64, t = threadIdx.x;
  const float* src = fup + (long)b * Cn * HWn + p0;
  for (int i = t; i < 128 * 64; i += 256) {
    int c = i >> 6, p = i & 63;
    xs[c][p] = src[(long)c * HWn + p];
  }
  __syncthreads();
  for (int i = t; i < 1024; i += 256) {
    int p = i >> 4, ch = (i & 15) * 8;
    uint4 pk;
    pk.x = pack2(xs[ch + 0][p], xs[ch + 1][p]);
    pk.y = pack2(xs[ch + 2][p], xs[ch + 3][p]);
    pk.z = pack2(xs[ch + 4][p], xs[ch + 5][p]);
    pk.w = pack2(xs[ch + 6][p], xs[ch + 7][p]);
    *(uint4*)(fupb + (((long)(b * HWn + p0 + p)) << 7) + ch) = pk;
  }
}

// ---------------- feat_arm ----------------
__global__ __launch_bounds__(256) void k_farm(const float* __restrict__ fl,
                                              const float* __restrict__ w1t,
                                              float* __restrict__ farm) {
  const int t = threadIdx.x;
  const int b = blockIdx.z, og = blockIdx.y;
  const int pos = blockIdx.x * 256 + t;
  const float* x = fl + (long)b * Cn * HWn + pos;
  const float* wb = w1t + (long)b * Cn * Cn + og * 8;
  float acc[8];
#pragma unroll
  for (int o = 0; o < 8; ++o) acc[o] = 0.f;
  for (int c = 0; c < Cn; ++c) {
    float xv = x[(long)c * HWn];
    const float4* w4 = (const float4*)(wb + (long)c * Cn);
    float4 wa = w4[0], wc = w4[1];
    acc[0] += xv * wa.x; acc[1] += xv * wa.y; acc[2] += xv * wa.z; acc[3] += xv * wa.w;
    acc[4] += xv * wc.x; acc[5] += xv * wc.y; acc[6] += xv * wc.z; acc[7] += xv * wc.w;
  }
#pragma unroll
  for (int o = 0; o < 8; ++o)
    farm[(long)(b * Cn + og * 8 + o) * HWn + pos] = acc[o];
}

// ---------------- off_feat -> bf16 NHWC [b][pos][c] ----------------
__global__ __launch_bounds__(256) void k_offf(const float* __restrict__ arm,
                                              const float* __restrict__ fup,
                                              const float* __restrict__ wot,
                                              unsigned short* __restrict__ oftb) {
  const int t = threadIdx.x;
  const int b = blockIdx.z, og = blockIdx.y;
  const int pos = blockIdx.x * 256 + t;
  const float* xa = arm + (long)b * Cn * HWn + pos;
  const float* xu = fup + (long)b * Cn * HWn + pos;
  const float* wg = wot + og * 8;
  float acc[8];
#pragma unroll
  for (int o = 0; o < 8; ++o) acc[o] = 0.f;
  for (int c = 0; c < Cn; ++c) {
    float xv = xa[(long)c * HWn];
    const float4* w4 = (const float4*)(wg + (long)c * Cn);
    float4 wa = w4[0], wc = w4[1];
    acc[0] += xv * wa.x; acc[1] += xv * wa.y; acc[2] += xv * wa.z; acc[3] += xv * wa.w;
    acc[4] += xv * wc.x; acc[5] += xv * wc.y; acc[6] += xv * wc.z; acc[7] += xv * wc.w;
  }
  for (int c = 0; c < Cn; ++c) {
    float xv = xu[(long)c * HWn];
    const float4* w4 = (const float4*)(wg + (long)(Cn + c) * Cn);
    float4 wa = w4[0], wc = w4[1];
    acc[0] += xv * wa.x; acc[1] += xv * wa.y; acc[2] += xv * wa.z; acc[3] += xv * wa.w;
    acc[4] += xv * wc.x; acc[5] += xv * wc.y; acc[6] += xv * wc.z; acc[7] += xv * wc.w;
  }
  uint4 pk;
  pk.x = pack2(acc[0], acc[1]); pk.y = pack2(acc[2], acc[3]);
  pk.z = pack2(acc[4], acc[5]); pk.w = pack2(acc[6], acc[7]);
  *(uint4*)(oftb + (((long)b * HWn + pos) << 7) + og * 8) = pk;
}

// ---------------- 3x3 conv via bf16 MFMA, LDS-staged weights -> om ----------------
// om output layout: [b][h][216][64] (w-contiguous rows for k_dcn coalescing).
__global__ __launch_bounds__(256) void k_convcm(const unsigned short* __restrict__ xb,
                                                const unsigned short* __restrict__ wsl,
                                                const float* __restrict__ bcm,
                                                float* __restrict__ om) {
  __shared__ unsigned short wlds[2][14336];   // 2 x 28,672 B
  const int h = blockIdx.x, b = blockIdx.y;
  const int t = threadIdx.x, lane = t & 63, wv = t >> 6;
  const int mi = wv & 1, ni = wv >> 1;
  const int lm = lane & 15, lh = lane >> 4;

  f32x4 acc[2][7];
#pragma unroll
  for (int mt = 0; mt < 2; ++mt)
#pragma unroll
    for (int nt = 0; nt < 7; ++nt) acc[mt][nt] = (f32x4){0.f, 0.f, 0.f, 0.f};

  auto stage = [&](int s, int bufi) {
    const char* src = (const char*)(wsl + (long)s * 14336);
    char* dstb = (char*)&wlds[bufi][0];
#pragma unroll
    for (int i2 = 0; i2 < 7; ++i2) {
      int off = (wv * 7 + i2) * 1024;
      GLOAD_LDS16(src + off + lane * 16, dstb + off);
    }
  };

  stage(0, 0);
  __syncthreads();

  for (int s = 0; s < 18; ++s) {
    const int cur = s & 1;
    if (s < 17) stage(s + 1, cur ^ 1);
    const int tap = s >> 1, ck = s & 1;
    const int ky = tap / 3, kx = tap % 3;
    const int gy = h + ky - 1;
    const bool gyok = ((unsigned)gy < (unsigned)Hn);
    const int gyc = min(max(gy, 0), Hn - 1);

    bf16x8 af[2][2];
#pragma unroll
    for (int mt = 0; mt < 2; ++mt) {
      int wpos = mi * 32 + mt * 16 + lm;
      int gx = wpos + kx - 1;
      bool ok = gyok && ((unsigned)gx < (unsigned)Wn);
      int gxc = min(max(gx, 0), Wn - 1);
      const unsigned short* ap = xb + (((long)(b * HWn + gyc * Wn + gxc)) << 7)
                                    + ck * 64 + lh * 8;
#pragma unroll
      for (int ksub = 0; ksub < 2; ++ksub) {
        bf16x8 v = *(const bf16x8*)(ap + ksub * 32);
        af[mt][ksub] = ok ? v : (bf16x8)(short)0;
      }
    }

    const char* wbase = (const char*)&wlds[cur][0];
#pragma unroll
    for (int ksub = 0; ksub < 2; ++ksub) {
      int jj = ksub * 4 + lh;
#pragma unroll
      for (int nt = 0; nt < 7; ++nt) {
        int oc = ni * 112 + nt * 16 + lm;
        bf16x8 bfv = *(const bf16x8*)(wbase + oc * 128 + ((jj ^ (oc & 7)) << 4));
#pragma unroll
        for (int mt = 0; mt < 2; ++mt)
          acc[mt][nt] = __builtin_amdgcn_mfma_f32_16x16x32_bf16(
              af[mt][ksub], bfv, acc[mt][nt], 0, 0, 0);
      }
    }
    __syncthreads();
  }

#pragma unroll
  for (int nt = 0; nt < 7; ++nt) {
    int ch = ni * 112 + nt * 16 + lm;
    if (ch >= CMn) continue;
    float bias = bcm[ch];
#pragma unroll
    for (int mt = 0; mt < 2; ++mt) {
#pragma unroll
      for (int r = 0; r < 4; ++r) {
        int w = mi * 32 + mt * 16 + lh * 4 + r;
        float v = acc[mt][nt][r] + bias;
        if (ch >= 144) v = 1.0f / (1.0f + expf(-v));
        om[((long)((b * Hn + h) * CMn + ch) << 6) + w] = v;
      }
    }
  }
}

// ---------------- fused DCN v2: reg-hoisted om + pipelined gather + MFMA ----------------
__global__ __launch_bounds__(256) void k_dcn(const float* __restrict__ om,
                                             const unsigned short* __restrict__ fupb,
                                             const unsigned short* __restrict__ wdb,
                                             const float* __restrict__ bdc,
                                             const float* __restrict__ farm,
                                             void* __restrict__ out,
                                             const int* __restrict__ flagp) {
  __shared__ char valb[32 * 272];
  const int h = blockIdx.x, b = blockIdx.y, w0 = blockIdx.z * 32;
  const int t = threadIdx.x;
  const int lane = t & 63, wid = t >> 6;
  const int gw = t & 31, g = t >> 5;
  f32x4 acc[2][2];
#pragma unroll
  for (int mt = 0; mt < 2; ++mt)
#pragma unroll
    for (int nt = 0; nt < 2; ++nt) acc[mt][nt] = (f32x4){0.f, 0.f, 0.f, 0.f};

  const unsigned short* fb = fupb + ((long)b * HWn << 7) + g * 16;
  const int wcol = w0 + gw;

  // hoist all 27 om values (coalesced: w-contiguous rows)
  const float* omr = om + ((long)(b * Hn + h) * CMn << 6) + wcol;
  float oyv[9], oxv[9], mkv[9];
#pragma unroll
  for (int k = 0; k < Kn; ++k) {
    int ch = g * Kn + k;
    oyv[k] = omr[ch << 6];
    oxv[k] = omr[(72 + ch) << 6];
    mkv[k] = omr[(144 + ch) << 6];
  }

  union U4 { uint4 q; unsigned short s[8]; };
  U4 r0a, r0b, r1a, r1b, r2a, r2b, r3a, r3b;
  float wq0, wq1, wq2, wq3;

  auto calc_issue = [&](int k) {
    float py = (float)(h + k / 3 - 1) + oyv[k];
    float px = (float)(wcol + k % 3 - 1) + oxv[k];
    float mk = mkv[k];
    float fy = floorf(py), fx = floorf(px);
    float ly = py - fy, lx = px - fx;
    int y0 = (int)fy, x0 = (int)fx, y1 = y0 + 1, x1 = x0 + 1;
    float vy0 = (y0 >= 0 && y0 < Hn) ? 1.f : 0.f;
    float vy1 = (y1 >= 0 && y1 < Hn) ? 1.f : 0.f;
    float vx0 = (x0 >= 0 && x0 < Wn) ? 1.f : 0.f;
    float vx1 = (x1 >= 0 && x1 < Wn) ? 1.f : 0.f;
    int cy0 = min(max(y0, 0), Hn - 1), cy1 = min(max(y1, 0), Hn - 1);
    int cx0 = min(max(x0, 0), Wn - 1), cx1 = min(max(x1, 0), Wn - 1);
    wq0 = (1.f - ly) * (1.f - lx) * vy0 * vx0 * mk;
    wq1 = (1.f - ly) * lx * vy0 * vx1 * mk;
    wq2 = ly * (1.f - lx) * vy1 * vx0 * mk;
    wq3 = ly * lx * vy1 * vx1 * mk;
    const unsigned short* q0 = fb + ((long)(cy0 * Wn + cx0) << 7);
    const unsigned short* q1 = fb + ((long)(cy0 * Wn + cx1) << 7);
    const unsigned short* q2 = fb + ((long)(cy1 * Wn + cx0) << 7);
    const unsigned short* q3 = fb + ((long)(cy1 * Wn + cx1) << 7);
    r0a.q = *(const uint4*)q0;  r0b.q = *(const uint4*)(q0 + 8);
    r1a.q = *(const uint4*)q1;  r1b.q = *(const uint4*)(q1 + 8);
    r2a.q = *(const uint4*)q2;  r2b.q = *(const uint4*)(q2 + 8);
    r3a.q = *(const uint4*)q3;  r3b.q = *(const uint4*)(q3 + 8);
  };

  calc_issue(0);

#pragma unroll
  for (int k = 0; k < Kn; ++k) {
    // consume current corners (waits on their loads), save weights
    float cw0 = wq0, cw1 = wq1, cw2 = wq2, cw3 = wq3;
    float v[16];
#pragma unroll
    for (int j = 0; j < 8; ++j)
      v[j] = cw0 * b2f(r0a.s[j]) + cw1 * b2f(r1a.s[j]) +
             cw2 * b2f(r2a.s[j]) + cw3 * b2f(r3a.s[j]);
#pragma unroll
    for (int j = 0; j < 8; ++j)
      v[8 + j] = cw0 * b2f(r0b.s[j]) + cw1 * b2f(r1b.s[j]) +
                 cw2 * b2f(r2b.s[j]) + cw3 * b2f(r3b.s[j]);
    // prefetch next tap's corners (in flight across MFMA phase)
    if (k < Kn - 1) calc_issue(k + 1);
    uint4 pk0, pk1;
    pk0.x = pack2(v[0], v[1]);  pk0.y = pack2(v[2], v[3]);
    pk0.z = pack2(v[4], v[5]);  pk0.w = pack2(v[6], v[7]);
    pk1.x = pack2(v[8], v[9]);  pk1.y = pack2(v[10], v[11]);
    pk1.z = pack2(v[12], v[13]); pk1.w = pack2(v[14], v[15]);
    char* row = valb + gw * 272 + g * 32;
    *(uint4*)row = pk0;
    *(uint4*)(row + 16) = pk1;
    __syncthreads();
    const unsigned short* wkb = wdb + (long)k * Cn * Cn;
#pragma unroll
    for (int ks = 0; ks < 4; ++ks) {
      int c0 = ks * 32 + 8 * (lane >> 4);
      bf16x8 af[2], bfv[2];
#pragma unroll
      for (int mt = 0; mt < 2; ++mt) {
        int lw = mt * 16 + (lane & 15);
        af[mt] = *(const bf16x8*)(valb + lw * 272 + c0 * 2);
      }
#pragma unroll
      for (int nt = 0; nt < 2; ++nt) {
        int o = wid * 32 + nt * 16 + (lane & 15);
        bfv[nt] = *(const bf16x8*)(wkb + (long)o * Cn + c0);
      }
#pragma unroll
      for (int mt = 0; mt < 2; ++mt)
#pragma unroll
        for (int nt = 0; nt < 2; ++nt)
          acc[mt][nt] = __builtin_amdgcn_mfma_f32_16x16x32_bf16(
              af[mt], bfv[nt], acc[mt][nt], 0, 0, 0);
    }
    __syncthreads();
  }

  bool isbf = (*flagp != 0);
#pragma unroll
  for (int nt = 0; nt < 2; ++nt) {
    int o = wid * 32 + nt * 16 + (lane & 15);
    float bias = bdc[o];
#pragma unroll
    for (int mt = 0; mt < 2; ++mt) {
#pragma unroll
      for (int r = 0; r < 4; ++r) {
        int w = w0 + mt * 16 + (lane >> 4) * 4 + r;
        long oi = (long)(b * Cn + o) * HWn + h * Wn + w;
        float v = acc[mt][nt][r] + bias;
        v = fmaxf(v, 0.f) + farm[oi];
        if (isbf) ((__hip_bfloat16*)out)[oi] = __float2bfloat16(v);
        else      ((float*)out)[oi] = v;
      }
    }
  }
}

// ---------------- launcher ----------------
extern "C" void kernel_launch(void* const* d_in, const int* in_sizes, int n_in,
                              void* d_out, int out_size, void* d_ws, size_t ws_size,
                              hipStream_t stream) {
  (void)in_sizes; (void)n_in; (void)out_size; (void)ws_size;
  const void* feat_l  = d_in[0];
  const void* feat_s  = d_in[1];
  const void* w_atten = d_in[2];
  const void* w_fsm   = d_in[3];
  const void* w_off   = d_in[4];
  const void* w_cm    = d_in[5];
  const void* b_cm    = d_in[6];
  const void* w_dcn   = d_in[7];
  const void* b_dcn   = d_in[8];
  float* ws = (float*)d_ws;
  int* flagw = (int*)d_ws;
  const int* flag = (const int*)d_ws;
  unsigned short* wdb = (unsigned short*)(ws + OFF_WDT);
  unsigned short* wcb = (unsigned short*)(ws + OFF_WCT);
  unsigned short* oftb = (unsigned short*)(ws + OFF_OFT);
  unsigned short* fupb = (unsigned short*)(ws + OFF_FUPB);

  k_detect<<<1, 256, 0, stream>>>((const unsigned int*)feat_l, flagw);
  k_cvt<<<2048, 256, 0, stream>>>(feat_l, ws + OFF_FL, Bn * Cn * HWn, flag);
  k_cvt<<<512, 256, 0, stream>>>(feat_s, ws + OFF_FS, Bn * Cn * HWs, flag);
  k_cvt<<<1, 256, 0, stream>>>(b_cm, ws + OFF_BCM, CMn, flag);
  k_cvt<<<1, 256, 0, stream>>>(b_dcn, ws + OFF_BDC, Cn, flag);
  k_woffT<<<(2 * Cn * Cn + 255) / 256, 256, 0, stream>>>(w_off, ws + OFF_WOT, flag);
  k_wcmB<<<(18 * 224 * 64 + 255) / 256, 256, 0, stream>>>(w_cm, wcb, flag);
  k_wdcnB<<<(Kn * Cn * Cn + 255) / 256, 256, 0, stream>>>(w_dcn, wdb, flag);
  k_gap<<<Bn * Cn, 256, 0, stream>>>(ws + OFF_FL, ws + OFF_GAP);
  k_atten<<<4, 256, 0, stream>>>(ws + OFF_GAP, w_atten, ws + OFF_AT, flag);
  k_w1t<<<(Bn * Cn * Cn + 255) / 256, 256, 0, stream>>>(w_fsm, ws + OFF_AT, ws + OFF_W1T, flag);
  k_up<<<(Bn * Cn * HWn + 255) / 256, 256, 0, stream>>>(ws + OFF_FS, ws + OFF_FUP);
  k_upb<<<dim3(64, 8), 256, 0, stream>>>(ws + OFF_FUP, fupb);
  k_farm<<<dim3(16, 16, 8), 256, 0, stream>>>(ws + OFF_FL, ws + OFF_W1T, ws + OFF_ARM);
  k_offf<<<dim3(16, 16, 8), 256, 0, stream>>>(ws + OFF_ARM, ws + OFF_FUP, ws + OFF_WOT, oftb);
  k_convcm<<<dim3(64, 8), 256, 0, stream>>>(oftb, wcb, ws + OFF_BCM, ws + OFF_OM);
  k_dcn<<<dim3(64, 8, 2), 256, 0, stream>>>(ws + OFF_OM, fupb, wdb,
                                            ws + OFF_BDC, ws + OFF_ARM, d_out, flag);
}